// Round 1
// baseline (1319.000 us; speedup 1.0000x reference)
//
#include <hip/hip_runtime.h>
#include <cstdint>
#include <cstddef>

static __device__ __forceinline__ float lrelu(float x){ return x > 0.f ? x : 0.2f*x; }

// ---------------- CSR build ----------------
__global__ void k_hist(const int* __restrict__ dst, int E, int* __restrict__ counts){
  int i = blockIdx.x*blockDim.x + threadIdx.x;
  if (i < E) atomicAdd(&counts[dst[i]], 1);
}

__global__ void k_scan_block(const int* __restrict__ counts, int n, int* __restrict__ rowptr, int* __restrict__ bsums){
  __shared__ int buf[1024];
  int tid = threadIdx.x;
  int i = blockIdx.x*1024 + tid;
  int v = (i < n) ? counts[i] : 0;
  buf[tid] = v;
  __syncthreads();
  for (int off = 1; off < 1024; off <<= 1){
    int t = (tid >= off) ? buf[tid-off] : 0;
    __syncthreads();
    buf[tid] += t;
    __syncthreads();
  }
  if (i < n) rowptr[i] = buf[tid] - v;   // local exclusive
  if (tid == 1023) bsums[blockIdx.x] = buf[1023];
}

__global__ void k_scan_sums(int* bsums, int nb){
  if (threadIdx.x == 0 && blockIdx.x == 0){
    int run = 0;
    for (int i = 0; i < nb; i++){ int t = bsums[i]; bsums[i] = run; run += t; }
  }
}

__global__ void k_scan_add(int* __restrict__ rowptr, const int* __restrict__ bsums, int n, int E){
  int i = blockIdx.x*blockDim.x + threadIdx.x;
  if (i < n) rowptr[i] += bsums[i >> 10];
  if (i == n) rowptr[n] = E;
}

__global__ void k_scatter(const int* __restrict__ src, const int* __restrict__ dst, int E,
                          const int* __restrict__ rowptr, int* __restrict__ cursor, int* __restrict__ ssrc){
  int i = blockIdx.x*blockDim.x + threadIdx.x;
  if (i < E){
    int d = dst[i];
    int p = atomicAdd(&cursor[d], 1);
    ssrc[rowptr[d] + p] = src[i];
  }
}

// ---------------- fp32 tiled GEMM: Y[N,F] = X[N,K] @ W[K,F] ----------------
__global__ __launch_bounds__(256) void k_gemm(const float* __restrict__ X, const float* __restrict__ W,
                                              float* __restrict__ Y, int N, int K, int F){
  __shared__ float As[16][65];
  __shared__ float Bs[16][65];
  int bm = blockIdx.x*64, bn = blockIdx.y*64;
  int t = threadIdx.x;
  int tm = t & 15, tn = t >> 4;
  int alr = t >> 2, alk = (t & 3)*4;       // A: 64 rows x 16 k
  int blk = t >> 4, bln = (t & 15)*4;      // B: 16 k x 64 cols
  float acc[4][4] = {};
  for (int k0 = 0; k0 < K; k0 += 16){
    int gr = bm + alr;
    float4 av = {0,0,0,0};
    if (gr < N) av = *reinterpret_cast<const float4*>(X + (size_t)gr*K + k0 + alk);
    As[alk+0][alr]=av.x; As[alk+1][alr]=av.y; As[alk+2][alr]=av.z; As[alk+3][alr]=av.w;
    int gk = k0 + blk;
    float4 bv = {0,0,0,0};
    if (((F & 3) == 0) && (bn + bln + 3 < F)){
      bv = *reinterpret_cast<const float4*>(W + (size_t)gk*F + bn + bln);
    } else {
      float tv0 = (bn+bln+0 < F) ? W[(size_t)gk*F + bn+bln+0] : 0.f;
      float tv1 = (bn+bln+1 < F) ? W[(size_t)gk*F + bn+bln+1] : 0.f;
      float tv2 = (bn+bln+2 < F) ? W[(size_t)gk*F + bn+bln+2] : 0.f;
      float tv3 = (bn+bln+3 < F) ? W[(size_t)gk*F + bn+bln+3] : 0.f;
      bv.x=tv0; bv.y=tv1; bv.z=tv2; bv.w=tv3;
    }
    Bs[blk][bln+0]=bv.x; Bs[blk][bln+1]=bv.y; Bs[blk][bln+2]=bv.z; Bs[blk][bln+3]=bv.w;
    __syncthreads();
    #pragma unroll
    for (int kk=0; kk<16; kk++){
      float a[4], b[4];
      #pragma unroll
      for (int j=0;j<4;j++){ a[j] = As[kk][tm*4+j]; b[j] = Bs[kk][tn*4+j]; }
      #pragma unroll
      for (int i2=0;i2<4;i2++)
        #pragma unroll
        for (int j=0;j<4;j++) acc[i2][j] += a[i2]*b[j];
    }
    __syncthreads();
  }
  #pragma unroll
  for (int i2=0;i2<4;i2++){
    int r = bm + tm*4 + i2;
    if (r < N){
      #pragma unroll
      for (int j=0;j<4;j++){
        int c = bn + tn*4 + j;
        if (c < F) Y[(size_t)r*F + c] = acc[i2][j];
      }
    }
  }
}

// ---------------- attention logits per node ----------------
__global__ void k_al(const float* __restrict__ xl, const float* __restrict__ asrc, const float* __restrict__ adst,
                     float* __restrict__ als, float* __restrict__ ald, int N, int H, int C){
  int i = blockIdx.x*blockDim.x + threadIdx.x;
  if (i >= N*H) return;
  int h = i % H;
  const float* row = xl + (size_t)(i/H)*H*C + (size_t)h*C;
  float s = 0.f, d = 0.f;
  for (int c = 0; c < C; c++){ float v = row[c]; s += v*asrc[h*C+c]; d += v*adst[h*C+c]; }
  als[i] = s; ald[i] = d;
}

// ---------------- GAT aggregation: one block per dst node ----------------
template<int H, int C>
__global__ void k_gat(const int* __restrict__ rowptr, const int* __restrict__ ssrc,
                      const float* __restrict__ xl, const float* __restrict__ als, const float* __restrict__ ald,
                      float* __restrict__ out){
  const int F = H*C;
  int node = blockIdx.x;
  int tid = threadIdx.x;
  if (tid >= F) return;
  int h = tid / C;
  int beg = rowptr[node], end = rowptr[node+1];
  float adst = ald[node*H + h];
  float m = -1e30f;
  for (int e=beg; e<end; e++){
    int s = ssrc[e];
    float a = lrelu(als[s*H + h] + adst);
    m = fmaxf(m, a);
  }
  float ssum = 0.f;
  for (int e=beg; e<end; e++){
    int s = ssrc[e];
    float a = lrelu(als[s*H + h] + adst);
    ssum += __expf(a - m);
  }
  float inv = 1.f / (ssum + 1e-16f);
  float acc = 0.f;
  for (int e=beg; e<end; e++){
    int s = ssrc[e];
    float a = lrelu(als[s*H + h] + adst);
    acc += __expf(a - m) * inv * xl[(size_t)s*F + tid];
  }
  out[(size_t)node*F + tid] = acc;
}

// ---------------- BatchNorm ----------------
__global__ void k_bnstats(const float* __restrict__ x, int N, int F, float* __restrict__ sums, float* __restrict__ sumsq){
  int f = threadIdx.x;
  if (f >= F) return;
  int r0 = blockIdx.x*128;
  int r1 = min(r0+128, N);
  float s=0.f, s2=0.f;
  for (int r=r0; r<r1; r++){ float v = x[(size_t)r*F + f]; s += v; s2 += v*v; }
  atomicAdd(&sums[f], s);
  atomicAdd(&sumsq[f], s2);
}

__global__ void k_bnapply_elu(const float* __restrict__ x, const float* __restrict__ sums, const float* __restrict__ sumsq,
                              const float* __restrict__ g, const float* __restrict__ beta,
                              float* __restrict__ y, int N, int F){
  int i = blockIdx.x*blockDim.x + threadIdx.x;
  if (i >= N*F) return;
  int f = i % F;
  float mu = sums[f] / (float)N;
  float var = sumsq[f] / (float)N - mu*mu;
  float inv = rsqrtf(var + 1e-5f);
  float v = (x[i]-mu)*inv*g[f] + beta[f];
  y[i] = v > 0.f ? v : (__expf(v) - 1.f);
}

// ---------------- final: +bias, log_softmax over 10 classes ----------------
__global__ void k_final(const float* __restrict__ x, const float* __restrict__ b3, float* __restrict__ out, int N){
  int n = blockIdx.x*blockDim.x + threadIdx.x;
  if (n >= N) return;
  float v[10];
  float m = -1e30f;
  #pragma unroll
  for (int c=0;c<10;c++){ v[c] = x[n*10+c] + b3[c]; m = fmaxf(m, v[c]); }
  float s = 0.f;
  #pragma unroll
  for (int c=0;c<10;c++) s += __expf(v[c]-m);
  float ls = logf(s);
  #pragma unroll
  for (int c=0;c<10;c++) out[n*10+c] = v[c] - m - ls;
}

extern "C" void kernel_launch(void* const* d_in, const int* in_sizes, int n_in,
                              void* d_out, int out_size, void* d_ws, size_t ws_size,
                              hipStream_t stream){
  const float* x   = (const float*)d_in[0];
  const int*  ei   = (const int*)d_in[1];
  const float* W1  = (const float*)d_in[2];
  const float* as1 = (const float*)d_in[3];
  const float* ad1 = (const float*)d_in[4];
  // d_in[5] = b1: cancels under BatchNorm (mean subtraction) -> skipped
  const float* g1  = (const float*)d_in[6];
  const float* be1 = (const float*)d_in[7];
  const float* W2  = (const float*)d_in[8];
  const float* as2 = (const float*)d_in[9];
  const float* ad2 = (const float*)d_in[10];
  // d_in[11] = b2: cancels under BatchNorm -> skipped
  const float* g2  = (const float*)d_in[12];
  const float* be2 = (const float*)d_in[13];
  const float* W3  = (const float*)d_in[14];
  const float* as3 = (const float*)d_in[15];
  const float* ad3 = (const float*)d_in[16];
  const float* b3  = (const float*)d_in[17];
  float* out = (float*)d_out;
  (void)n_in; (void)out_size; (void)ws_size;

  int N = in_sizes[0] / 128;     // 50000
  int E = in_sizes[1] / 2;       // 850000
  const int* src = ei;
  const int* dst = ei + E;

  char* w = (char*)d_ws;
  size_t off = 0;
  auto alloc = [&](size_t bytes) -> void* {
    void* p = w + off;
    off += (bytes + 255) & ~(size_t)255;
    return p;
  };
  float* bufA  = (float*)alloc((size_t)N*256*4);   // xl (max 256 feats)
  float* bufB  = (float*)alloc((size_t)N*256*4);   // gat out
  float* bufC  = (float*)alloc((size_t)N*128*4);   // h1 / xl3
  float* als   = (float*)alloc((size_t)N*8*4);
  float* ald   = (float*)alloc((size_t)N*8*4);
  int* rowptr  = (int*)alloc((size_t)(N+1)*4);
  int* counts  = (int*)alloc((size_t)N*4);
  int* cursor  = (int*)alloc((size_t)N*4);
  int* ssrc    = (int*)alloc((size_t)E*4);
  int* bsums   = (int*)alloc(256*4);
  float* sums  = (float*)alloc(256*4);
  float* sumsq = (float*)alloc(256*4);

  // ---- CSR by dst (reused for all 3 layers) ----
  hipMemsetAsync(counts, 0, (size_t)N*4, stream);
  hipMemsetAsync(cursor, 0, (size_t)N*4, stream);
  k_hist<<<(E+255)/256, 256, 0, stream>>>(dst, E, counts);
  int nchunks = (N + 1023)/1024;
  k_scan_block<<<nchunks, 1024, 0, stream>>>(counts, N, rowptr, bsums);
  k_scan_sums<<<1, 64, 0, stream>>>(bsums, nchunks);
  k_scan_add<<<(N+1+255)/256, 256, 0, stream>>>(rowptr, bsums, N, E);
  k_scatter<<<(E+255)/256, 256, 0, stream>>>(src, dst, E, rowptr, cursor, ssrc);

  // ---- layer 1: x[ N,128 ] -> h1[ N,128 ] ----
  {
    const int K=128, F=128, H=8;
    dim3 g((N+63)/64, (F+63)/64);
    k_gemm<<<g, 256, 0, stream>>>(x, W1, bufA, N, K, F);
    k_al<<<(N*H+255)/256, 256, 0, stream>>>(bufA, as1, ad1, als, ald, N, H, 16);
    k_gat<8,16><<<N, 128, 0, stream>>>(rowptr, ssrc, bufA, als, ald, bufB);
    hipMemsetAsync(sums, 0, 256*4, stream);
    hipMemsetAsync(sumsq, 0, 256*4, stream);
    k_bnstats<<<(N+127)/128, F, 0, stream>>>(bufB, N, F, sums, sumsq);
    k_bnapply_elu<<<(int)(((size_t)N*F+255)/256), 256, 0, stream>>>(bufB, sums, sumsq, g1, be1, bufC, N, F);
  }
  // ---- layer 2: h1[ N,128 ] -> h2[ N,256 ] ----
  {
    const int K=128, F=256, H=8;
    dim3 g((N+63)/64, (F+63)/64);
    k_gemm<<<g, 256, 0, stream>>>(bufC, W2, bufA, N, K, F);
    k_al<<<(N*H+255)/256, 256, 0, stream>>>(bufA, as2, ad2, als, ald, N, H, 32);
    k_gat<8,32><<<N, 256, 0, stream>>>(rowptr, ssrc, bufA, als, ald, bufB);
    hipMemsetAsync(sums, 0, 256*4, stream);
    hipMemsetAsync(sumsq, 0, 256*4, stream);
    k_bnstats<<<(N+127)/128, F, 0, stream>>>(bufB, N, F, sums, sumsq);
    k_bnapply_elu<<<(int)(((size_t)N*F+255)/256), 256, 0, stream>>>(bufB, sums, sumsq, g2, be2, bufA, N, F);  // h2 -> bufA
  }
  // ---- layer 3: h2[ N,256 ] -> logits[ N,10 ] ----
  {
    const int K=256, F=10, H=1;
    dim3 g((N+63)/64, (F+63)/64);
    k_gemm<<<g, 256, 0, stream>>>(bufA, W3, bufC, N, K, F);
    k_al<<<(N*H+255)/256, 256, 0, stream>>>(bufC, as3, ad3, als, ald, N, H, 10);
    k_gat<1,10><<<N, 64, 0, stream>>>(rowptr, ssrc, bufC, als, ald, bufB);
    k_final<<<(N+255)/256, 256, 0, stream>>>(bufB, b3, out, N);
  }
}

// Round 7
// 1113.119 us; speedup vs baseline: 1.1850x; 1.1850x over previous
//
#include <hip/hip_runtime.h>
#include <hip/hip_bf16.h>
#include <cstdint>
#include <cstddef>

using bf16 = __hip_bfloat16;

static __device__ __forceinline__ float lrelu(float x){ return x > 0.f ? x : 0.2f*x; }
static __device__ __forceinline__ float b2f(bf16 v){ return __bfloat162float(v); }

// ---------------- CSR build ----------------
__global__ void k_hist(const int* __restrict__ dst, int E, int* __restrict__ counts){
  int i = blockIdx.x*blockDim.x + threadIdx.x;
  if (i < E) atomicAdd(&counts[dst[i]], 1);
}

__global__ void k_scan_block(const int* __restrict__ counts, int n, int* __restrict__ rowptr, int* __restrict__ bsums){
  __shared__ int buf[1024];
  int tid = threadIdx.x;
  int i = blockIdx.x*1024 + tid;
  int v = (i < n) ? counts[i] : 0;
  buf[tid] = v;
  __syncthreads();
  for (int off = 1; off < 1024; off <<= 1){
    int t = (tid >= off) ? buf[tid-off] : 0;
    __syncthreads();
    buf[tid] += t;
    __syncthreads();
  }
  if (i < n) rowptr[i] = buf[tid] - v;   // local exclusive
  if (tid == 1023) bsums[blockIdx.x] = buf[1023];
}

__global__ void k_scan_sums(int* bsums, int nb){
  if (threadIdx.x == 0 && blockIdx.x == 0){
    int run = 0;
    for (int i = 0; i < nb; i++){ int t = bsums[i]; bsums[i] = run; run += t; }
  }
}

__global__ void k_scan_add(int* __restrict__ rowptr, const int* __restrict__ bsums, int n, int E){
  int i = blockIdx.x*blockDim.x + threadIdx.x;
  if (i < n) rowptr[i] += bsums[i >> 10];
  if (i == n) rowptr[n] = E;
}

__global__ void k_scatter(const int* __restrict__ src, const int* __restrict__ dst, int E,
                          const int* __restrict__ rowptr, int* __restrict__ cursor, int* __restrict__ ssrc){
  int i = blockIdx.x*blockDim.x + threadIdx.x;
  if (i < E){
    int d = dst[i];
    int p = atomicAdd(&cursor[d], 1);
    ssrc[rowptr[d] + p] = src[i];
  }
}

// ---------------- fp32 tiled GEMM: Y[N,F](bf16) = X[N,K] @ W[K,F] ----------------
__global__ __launch_bounds__(256) void k_gemm(const float* __restrict__ X, const float* __restrict__ W,
                                              bf16* __restrict__ Y, int N, int K, int F){
  __shared__ float As[16][65];
  __shared__ float Bs[16][65];
  int bm = blockIdx.x*64, bn = blockIdx.y*64;
  int t = threadIdx.x;
  int tm = t & 15, tn = t >> 4;
  int alr = t >> 2, alk = (t & 3)*4;       // A: 64 rows x 16 k
  int blk = t >> 4, bln = (t & 15)*4;      // B: 16 k x 64 cols
  float acc[4][4] = {};
  for (int k0 = 0; k0 < K; k0 += 16){
    int gr = bm + alr;
    float4 av = {0,0,0,0};
    if (gr < N) av = *reinterpret_cast<const float4*>(X + (size_t)gr*K + k0 + alk);
    As[alk+0][alr]=av.x; As[alk+1][alr]=av.y; As[alk+2][alr]=av.z; As[alk+3][alr]=av.w;
    int gk = k0 + blk;
    float4 bv = {0,0,0,0};
    if (((F & 3) == 0) && (bn + bln + 3 < F)){
      bv = *reinterpret_cast<const float4*>(W + (size_t)gk*F + bn + bln);
    } else {
      float tv0 = (bn+bln+0 < F) ? W[(size_t)gk*F + bn+bln+0] : 0.f;
      float tv1 = (bn+bln+1 < F) ? W[(size_t)gk*F + bn+bln+1] : 0.f;
      float tv2 = (bn+bln+2 < F) ? W[(size_t)gk*F + bn+bln+2] : 0.f;
      float tv3 = (bn+bln+3 < F) ? W[(size_t)gk*F + bn+bln+3] : 0.f;
      bv.x=tv0; bv.y=tv1; bv.z=tv2; bv.w=tv3;
    }
    Bs[blk][bln+0]=bv.x; Bs[blk][bln+1]=bv.y; Bs[blk][bln+2]=bv.z; Bs[blk][bln+3]=bv.w;
    __syncthreads();
    #pragma unroll
    for (int kk=0; kk<16; kk++){
      float a[4], b[4];
      #pragma unroll
      for (int j=0;j<4;j++){ a[j] = As[kk][tm*4+j]; b[j] = Bs[kk][tn*4+j]; }
      #pragma unroll
      for (int i2=0;i2<4;i2++)
        #pragma unroll
        for (int j=0;j<4;j++) acc[i2][j] += a[i2]*b[j];
    }
    __syncthreads();
  }
  #pragma unroll
  for (int i2=0;i2<4;i2++){
    int r = bm + tm*4 + i2;
    if (r < N){
      #pragma unroll
      for (int j=0;j<4;j++){
        int c = bn + tn*4 + j;
        if (c < F) Y[(size_t)r*F + c] = __float2bfloat16(acc[i2][j]);
      }
    }
  }
}

// ---------------- attention logits per node ----------------
__global__ void k_al(const bf16* __restrict__ xl, const float* __restrict__ asrc, const float* __restrict__ adst,
                     float* __restrict__ als, float* __restrict__ ald, int N, int H, int C){
  int i = blockIdx.x*blockDim.x + threadIdx.x;
  if (i >= N*H) return;
  int h = i % H;
  const bf16* row = xl + (size_t)(i/H)*H*C + (size_t)h*C;
  float s = 0.f, d = 0.f;
  for (int c = 0; c < C; c++){ float v = b2f(row[c]); s += v*asrc[h*C+c]; d += v*adst[h*C+c]; }
  als[i] = s; ald[i] = d;
}

// ---------------- softmax coefficients per (dst node, head), CSR-ordered ----------------
// coef[p*H + h] = exp(lrelu(als[src]+ald[dst]) - max) / (sum + 1e-16)
template<int H>
__global__ void k_coef(const int* __restrict__ rowptr, const int* __restrict__ ssrc,
                       const float* __restrict__ als, const float* __restrict__ ald,
                       float* __restrict__ coef, int N){
  int i = blockIdx.x*blockDim.x + threadIdx.x;
  if (i >= N*H) return;
  int node = i / H;
  int h = i - node*H;
  int beg = rowptr[node], end = rowptr[node+1];
  float ad = ald[i];
  float m = -1e30f;
  for (int p = beg; p < end; p++){
    float a = lrelu(als[ssrc[p]*H + h] + ad);
    coef[(size_t)p*H + h] = a;
    m = fmaxf(m, a);
  }
  float s = 0.f;
  for (int p = beg; p < end; p++){
    float w = __expf(coef[(size_t)p*H + h] - m);
    coef[(size_t)p*H + h] = w;
    s += w;
  }
  float inv = 1.f / (s + 1e-16f);
  for (int p = beg; p < end; p++) coef[(size_t)p*H + h] *= inv;
}

// ---------------- GAT aggregation: pure gather-FMA ----------------
// NPB nodes per block; F = H*C threads per node.
template<int H, int C, int NPB>
__global__ void k_gat2(const int* __restrict__ rowptr, const int* __restrict__ ssrc,
                       const bf16* __restrict__ xl, const float* __restrict__ coef,
                       float* __restrict__ out, int N){
  const int F = H*C;
  int tid = threadIdx.x;
  int node = blockIdx.x*NPB + tid/F;
  int lt = tid - (tid/F)*F;
  if (node >= N) return;
  int h = lt / C;
  int beg = rowptr[node], end = rowptr[node+1];
  float acc = 0.f;
  for (int p = beg; p < end; p++){
    int si = ssrc[p];
    float c = coef[(size_t)p*H + h];
    acc += c * b2f(xl[(size_t)si*F + lt]);
  }
  out[(size_t)node*F + lt] = acc;
}

// ---------------- BatchNorm ----------------
__global__ void k_bnstats(const float* __restrict__ x, int N, int F, float* __restrict__ sums, float* __restrict__ sumsq){
  int f = threadIdx.x;
  if (f >= F) return;
  int r0 = blockIdx.x*128;
  int r1 = min(r0+128, N);
  float s=0.f, s2=0.f;
  for (int r=r0; r<r1; r++){ float v = x[(size_t)r*F + f]; s += v; s2 += v*v; }
  atomicAdd(&sums[f], s);
  atomicAdd(&sumsq[f], s2);
}

__global__ void k_bnapply_elu(const float* __restrict__ x, const float* __restrict__ sums, const float* __restrict__ sumsq,
                              const float* __restrict__ g, const float* __restrict__ beta,
                              float* __restrict__ y, int N, int F){
  int i = blockIdx.x*blockDim.x + threadIdx.x;
  if (i >= N*F) return;
  int f = i % F;
  float mu = sums[f] / (float)N;
  float var = sumsq[f] / (float)N - mu*mu;
  float inv = rsqrtf(var + 1e-5f);
  float v = (x[i]-mu)*inv*g[f] + beta[f];
  y[i] = v > 0.f ? v : (__expf(v) - 1.f);
}

// ---------------- final: +bias, log_softmax over 10 classes ----------------
__global__ void k_final(const float* __restrict__ x, const float* __restrict__ b3, float* __restrict__ out, int N){
  int n = blockIdx.x*blockDim.x + threadIdx.x;
  if (n >= N) return;
  float v[10];
  float m = -1e30f;
  #pragma unroll
  for (int c=0;c<10;c++){ v[c] = x[n*10+c] + b3[c]; m = fmaxf(m, v[c]); }
  float s = 0.f;
  #pragma unroll
  for (int c=0;c<10;c++) s += __expf(v[c]-m);
  float ls = logf(s);
  #pragma unroll
  for (int c=0;c<10;c++) out[n*10+c] = v[c] - m - ls;
}

extern "C" void kernel_launch(void* const* d_in, const int* in_sizes, int n_in,
                              void* d_out, int out_size, void* d_ws, size_t ws_size,
                              hipStream_t stream){
  const float* x   = (const float*)d_in[0];
  const int*  ei   = (const int*)d_in[1];
  const float* W1  = (const float*)d_in[2];
  const float* as1 = (const float*)d_in[3];
  const float* ad1 = (const float*)d_in[4];
  // d_in[5] = b1: cancels under BatchNorm (mean subtraction) -> skipped
  const float* g1  = (const float*)d_in[6];
  const float* be1 = (const float*)d_in[7];
  const float* W2  = (const float*)d_in[8];
  const float* as2 = (const float*)d_in[9];
  const float* ad2 = (const float*)d_in[10];
  // d_in[11] = b2: cancels under BatchNorm -> skipped
  const float* g2  = (const float*)d_in[12];
  const float* be2 = (const float*)d_in[13];
  const float* W3  = (const float*)d_in[14];
  const float* as3 = (const float*)d_in[15];
  const float* ad3 = (const float*)d_in[16];
  const float* b3  = (const float*)d_in[17];
  float* out = (float*)d_out;
  (void)n_in; (void)out_size; (void)ws_size;

  int N = in_sizes[0] / 128;     // 50000
  int E = in_sizes[1] / 2;       // 850000
  const int* src = ei;
  const int* dst = ei + E;

  char* w = (char*)d_ws;
  size_t off = 0;
  auto alloc = [&](size_t bytes) -> void* {
    void* p = w + off;
    off += (bytes + 255) & ~(size_t)255;
    return p;
  };
  bf16* xlb    = (bf16*)alloc((size_t)N*256*2);    // GEMM out (bf16), per layer
  float* gout  = (float*)alloc((size_t)N*256*4);   // GAT out (fp32)
  float* hbuf  = (float*)alloc((size_t)N*256*4);   // BN+ELU out / next GEMM input; also aliases coef
  float* als   = (float*)alloc((size_t)N*8*4);
  float* ald   = (float*)alloc((size_t)N*8*4);
  int* rowptr  = (int*)alloc((size_t)(N+1)*4);
  int* counts  = (int*)alloc((size_t)N*4);
  int* cursor  = (int*)alloc((size_t)N*4);
  int* ssrc    = (int*)alloc((size_t)E*4);
  int* bsums   = (int*)alloc(256*4);
  float* sums  = (float*)alloc(256*4);
  float* sumsq = (float*)alloc(256*4);
  // coef aliases hbuf: live only between k_coef and k_gat2, which never
  // overlaps hbuf's live range (hbuf is consumed by k_gemm before k_coef
  // runs, and rewritten by k_bnapply_elu after k_gat2 completes).
  float* coef  = hbuf;   // E*H*4 <= 27.2 MB <= 51.2 MB

  // ---- CSR by dst (reused for all 3 layers) ----
  hipMemsetAsync(counts, 0, (size_t)N*4, stream);
  hipMemsetAsync(cursor, 0, (size_t)N*4, stream);
  k_hist<<<(E+255)/256, 256, 0, stream>>>(dst, E, counts);
  int nchunks = (N + 1023)/1024;
  k_scan_block<<<nchunks, 1024, 0, stream>>>(counts, N, rowptr, bsums);
  k_scan_sums<<<1, 64, 0, stream>>>(bsums, nchunks);
  k_scan_add<<<(N+1+255)/256, 256, 0, stream>>>(rowptr, bsums, N, E);
  k_scatter<<<(E+255)/256, 256, 0, stream>>>(src, dst, E, rowptr, cursor, ssrc);

  // ---- layer 1: x[N,128] -> h1[N,128] ----
  {
    const int K=128, F=128, H=8;
    dim3 g((N+63)/64, (F+63)/64);
    k_gemm<<<g, 256, 0, stream>>>(x, W1, xlb, N, K, F);
    k_al<<<(N*H+255)/256, 256, 0, stream>>>(xlb, as1, ad1, als, ald, N, H, 16);
    k_coef<8><<<(N*H+255)/256, 256, 0, stream>>>(rowptr, ssrc, als, ald, coef, N);
    k_gat2<8,16,2><<<(N+1)/2, 256, 0, stream>>>(rowptr, ssrc, xlb, coef, gout, N);
    hipMemsetAsync(sums, 0, 256*4, stream);
    hipMemsetAsync(sumsq, 0, 256*4, stream);
    k_bnstats<<<(N+127)/128, F, 0, stream>>>(gout, N, F, sums, sumsq);
    k_bnapply_elu<<<(int)(((size_t)N*F+255)/256), 256, 0, stream>>>(gout, sums, sumsq, g1, be1, hbuf, N, F);
  }
  // ---- layer 2: h1[N,128] -> h2[N,256] ----
  {
    const int K=128, F=256, H=8;
    dim3 g((N+63)/64, (F+63)/64);
    k_gemm<<<g, 256, 0, stream>>>(hbuf, W2, xlb, N, K, F);
    k_al<<<(N*H+255)/256, 256, 0, stream>>>(xlb, as2, ad2, als, ald, N, H, 32);
    k_coef<8><<<(N*H+255)/256, 256, 0, stream>>>(rowptr, ssrc, als, ald, coef, N);
    k_gat2<8,32,1><<<N, 256, 0, stream>>>(rowptr, ssrc, xlb, coef, gout, N);
    hipMemsetAsync(sums, 0, 256*4, stream);
    hipMemsetAsync(sumsq, 0, 256*4, stream);
    k_bnstats<<<(N+127)/128, F, 0, stream>>>(gout, N, F, sums, sumsq);
    k_bnapply_elu<<<(int)(((size_t)N*F+255)/256), 256, 0, stream>>>(gout, sums, sumsq, g2, be2, hbuf, N, F);
  }
  // ---- layer 3: h2[N,256] -> logits[N,10] ----
  {
    const int K=256, F=10, H=1;
    dim3 g((N+63)/64, (F+63)/64);
    k_gemm<<<g, 256, 0, stream>>>(hbuf, W3, xlb, N, K, F);
    k_al<<<(N*H+255)/256, 256, 0, stream>>>(xlb, as3, ad3, als, ald, N, H, 10);
    k_coef<1><<<(N+255)/256, 256, 0, stream>>>(rowptr, ssrc, als, ald, coef, N);
    k_gat2<1,10,32><<<(N+31)/32, 320, 0, stream>>>(rowptr, ssrc, xlb, coef, gout, N);
    k_final<<<(N+255)/256, 256, 0, stream>>>(gout, b3, out, N);
  }
}

// Round 8
// 856.072 us; speedup vs baseline: 1.5408x; 1.3003x over previous
//
#include <hip/hip_runtime.h>
#include <hip/hip_bf16.h>
#include <cstdint>
#include <cstddef>

using bf16 = __hip_bfloat16;

static __device__ __forceinline__ float lrelu(float x){ return x > 0.f ? x : 0.2f*x; }
static __device__ __forceinline__ float b2f(bf16 v){ return __bfloat162float(v); }

// ---------------- CSR build ----------------
__global__ void k_hist(const int* __restrict__ dst, int E, int* __restrict__ counts){
  int i = blockIdx.x*blockDim.x + threadIdx.x;
  if (i < E) atomicAdd(&counts[dst[i]], 1);
}

__global__ void k_scan_block(const int* __restrict__ counts, int n, int* __restrict__ rowptr, int* __restrict__ bsums){
  __shared__ int buf[1024];
  int tid = threadIdx.x;
  int i = blockIdx.x*1024 + tid;
  int v = (i < n) ? counts[i] : 0;
  buf[tid] = v;
  __syncthreads();
  for (int off = 1; off < 1024; off <<= 1){
    int t = (tid >= off) ? buf[tid-off] : 0;
    __syncthreads();
    buf[tid] += t;
    __syncthreads();
  }
  if (i < n) rowptr[i] = buf[tid] - v;   // local exclusive
  if (tid == 1023) bsums[blockIdx.x] = buf[1023];
}

__global__ void k_scan_sums(int* bsums, int nb){
  if (threadIdx.x == 0 && blockIdx.x == 0){
    int run = 0;
    for (int i = 0; i < nb; i++){ int t = bsums[i]; bsums[i] = run; run += t; }
  }
}

__global__ void k_scan_add(int* __restrict__ rowptr, const int* __restrict__ bsums, int n, int E){
  int i = blockIdx.x*blockDim.x + threadIdx.x;
  if (i < n) rowptr[i] += bsums[i >> 10];
  if (i == n) rowptr[n] = E;
}

__global__ void k_scatter(const int* __restrict__ src, const int* __restrict__ dst, int E,
                          const int* __restrict__ rowptr, int* __restrict__ cursor, int* __restrict__ ssrc){
  int i = blockIdx.x*blockDim.x + threadIdx.x;
  if (i < E){
    int d = dst[i];
    int p = atomicAdd(&cursor[d], 1);
    ssrc[rowptr[d] + p] = src[i];
  }
}

// ---------------- fp32 tiled GEMM: Y[N,F](bf16) = X[N,K] @ W[K,F] ----------------
__global__ __launch_bounds__(256) void k_gemm(const float* __restrict__ X, const float* __restrict__ W,
                                              bf16* __restrict__ Y, int N, int K, int F){
  __shared__ float As[16][65];
  __shared__ float Bs[16][65];
  int bm = blockIdx.x*64, bn = blockIdx.y*64;
  int t = threadIdx.x;
  int tm = t & 15, tn = t >> 4;
  int alr = t >> 2, alk = (t & 3)*4;       // A: 64 rows x 16 k
  int blk = t >> 4, bln = (t & 15)*4;      // B: 16 k x 64 cols
  float acc[4][4] = {};
  for (int k0 = 0; k0 < K; k0 += 16){
    int gr = bm + alr;
    float4 av = {0,0,0,0};
    if (gr < N) av = *reinterpret_cast<const float4*>(X + (size_t)gr*K + k0 + alk);
    As[alk+0][alr]=av.x; As[alk+1][alr]=av.y; As[alk+2][alr]=av.z; As[alk+3][alr]=av.w;
    int gk = k0 + blk;
    float4 bv = {0,0,0,0};
    if (((F & 3) == 0) && (bn + bln + 3 < F)){
      bv = *reinterpret_cast<const float4*>(W + (size_t)gk*F + bn + bln);
    } else {
      float tv0 = (bn+bln+0 < F) ? W[(size_t)gk*F + bn+bln+0] : 0.f;
      float tv1 = (bn+bln+1 < F) ? W[(size_t)gk*F + bn+bln+1] : 0.f;
      float tv2 = (bn+bln+2 < F) ? W[(size_t)gk*F + bn+bln+2] : 0.f;
      float tv3 = (bn+bln+3 < F) ? W[(size_t)gk*F + bn+bln+3] : 0.f;
      bv.x=tv0; bv.y=tv1; bv.z=tv2; bv.w=tv3;
    }
    Bs[blk][bln+0]=bv.x; Bs[blk][bln+1]=bv.y; Bs[blk][bln+2]=bv.z; Bs[blk][bln+3]=bv.w;
    __syncthreads();
    #pragma unroll
    for (int kk=0; kk<16; kk++){
      float a[4], b[4];
      #pragma unroll
      for (int j=0;j<4;j++){ a[j] = As[kk][tm*4+j]; b[j] = Bs[kk][tn*4+j]; }
      #pragma unroll
      for (int i2=0;i2<4;i2++)
        #pragma unroll
        for (int j=0;j<4;j++) acc[i2][j] += a[i2]*b[j];
    }
    __syncthreads();
  }
  #pragma unroll
  for (int i2=0;i2<4;i2++){
    int r = bm + tm*4 + i2;
    if (r < N){
      #pragma unroll
      for (int j=0;j<4;j++){
        int c = bn + tn*4 + j;
        if (c < F) Y[(size_t)r*F + c] = __float2bfloat16(acc[i2][j]);
      }
    }
  }
}

// ---------------- attention logits per node ----------------
__global__ void k_al(const bf16* __restrict__ xl, const float* __restrict__ asrc, const float* __restrict__ adst,
                     float* __restrict__ als, float* __restrict__ ald, int N, int H, int C){
  int i = blockIdx.x*blockDim.x + threadIdx.x;
  if (i >= N*H) return;
  int h = i % H;
  const bf16* row = xl + (size_t)(i/H)*H*C + (size_t)h*C;
  float s = 0.f, d = 0.f;
  for (int c = 0; c < C; c++){ float v = b2f(row[c]); s += v*asrc[h*C+c]; d += v*adst[h*C+c]; }
  als[i] = s; ald[i] = d;
}

// ---------------- softmax coefficients per (dst node, head), CSR-ordered ----------------
// coef[p*H + h] = exp(lrelu(als[src]+ald[dst]) - max) / (sum + 1e-16)
template<int H>
__global__ void k_coef(const int* __restrict__ rowptr, const int* __restrict__ ssrc,
                       const float* __restrict__ als, const float* __restrict__ ald,
                       float* __restrict__ coef, int N){
  int i = blockIdx.x*blockDim.x + threadIdx.x;
  if (i >= N*H) return;
  int node = i / H;
  int h = i - node*H;
  int beg = rowptr[node], end = rowptr[node+1];
  float ad = ald[i];
  float m = -1e30f;
  int p = beg;
  // pass 1: lrelu logits, running max — unrolled x4 for MLP on the als gather
  for (; p + 4 <= end; p += 4){
    int s0=ssrc[p], s1=ssrc[p+1], s2=ssrc[p+2], s3=ssrc[p+3];
    float a0 = lrelu(als[s0*H + h] + ad);
    float a1 = lrelu(als[s1*H + h] + ad);
    float a2 = lrelu(als[s2*H + h] + ad);
    float a3 = lrelu(als[s3*H + h] + ad);
    coef[(size_t)(p+0)*H + h] = a0;
    coef[(size_t)(p+1)*H + h] = a1;
    coef[(size_t)(p+2)*H + h] = a2;
    coef[(size_t)(p+3)*H + h] = a3;
    m = fmaxf(m, fmaxf(fmaxf(a0,a1), fmaxf(a2,a3)));
  }
  for (; p < end; p++){
    float a = lrelu(als[ssrc[p]*H + h] + ad);
    coef[(size_t)p*H + h] = a;
    m = fmaxf(m, a);
  }
  float s = 0.f;
  for (p = beg; p < end; p++){
    float w = __expf(coef[(size_t)p*H + h] - m);
    coef[(size_t)p*H + h] = w;
    s += w;
  }
  float inv = 1.f / (s + 1e-16f);
  for (p = beg; p < end; p++) coef[(size_t)p*H + h] *= inv;
}

// ---------------- GAT aggregation: pure gather-FMA, unrolled x4 for MLP ----------------
// NPB nodes per block; F = H*C threads per node.
template<int H, int C, int NPB>
__global__ void k_gat2(const int* __restrict__ rowptr, const int* __restrict__ ssrc,
                       const bf16* __restrict__ xl, const float* __restrict__ coef,
                       float* __restrict__ out, int N){
  const int F = H*C;
  int tid = threadIdx.x;
  int node = blockIdx.x*NPB + tid/F;
  int lt = tid - (tid/F)*F;
  if (node >= N) return;
  int h = lt / C;
  int beg = rowptr[node], end = rowptr[node+1];
  const float* cof = coef + h;
  const bf16* xlp = xl + lt;
  float acc = 0.f;
  int p = beg;
  for (; p + 4 <= end; p += 4){
    int s0=ssrc[p], s1=ssrc[p+1], s2=ssrc[p+2], s3=ssrc[p+3];
    float c0 = cof[(size_t)(p+0)*H];
    float c1 = cof[(size_t)(p+1)*H];
    float c2 = cof[(size_t)(p+2)*H];
    float c3 = cof[(size_t)(p+3)*H];
    float v0 = b2f(xlp[(size_t)s0*F]);
    float v1 = b2f(xlp[(size_t)s1*F]);
    float v2 = b2f(xlp[(size_t)s2*F]);
    float v3 = b2f(xlp[(size_t)s3*F]);
    acc += c0*v0;
    acc += c1*v1;
    acc += c2*v2;
    acc += c3*v3;
  }
  for (; p < end; p++){
    int si = ssrc[p];
    acc += cof[(size_t)p*H] * b2f(xlp[(size_t)si*F]);
  }
  out[(size_t)node*F + lt] = acc;
}

// ---------------- BatchNorm ----------------
__global__ void k_bnstats(const float* __restrict__ x, int N, int F, float* __restrict__ sums, float* __restrict__ sumsq){
  int f = threadIdx.x;
  if (f >= F) return;
  int r0 = blockIdx.x*128;
  int r1 = min(r0+128, N);
  float s=0.f, s2=0.f;
  for (int r=r0; r<r1; r++){ float v = x[(size_t)r*F + f]; s += v; s2 += v*v; }
  atomicAdd(&sums[f], s);
  atomicAdd(&sumsq[f], s2);
}

__global__ void k_bnapply_elu(const float* __restrict__ x, const float* __restrict__ sums, const float* __restrict__ sumsq,
                              const float* __restrict__ g, const float* __restrict__ beta,
                              float* __restrict__ y, int N, int F){
  int i = blockIdx.x*blockDim.x + threadIdx.x;
  if (i >= N*F) return;
  int f = i % F;
  float mu = sums[f] / (float)N;
  float var = sumsq[f] / (float)N - mu*mu;
  float inv = rsqrtf(var + 1e-5f);
  float v = (x[i]-mu)*inv*g[f] + beta[f];
  y[i] = v > 0.f ? v : (__expf(v) - 1.f);
}

// ---------------- final: +bias, log_softmax over 10 classes ----------------
__global__ void k_final(const float* __restrict__ x, const float* __restrict__ b3, float* __restrict__ out, int N){
  int n = blockIdx.x*blockDim.x + threadIdx.x;
  if (n >= N) return;
  float v[10];
  float m = -1e30f;
  #pragma unroll
  for (int c=0;c<10;c++){ v[c] = x[n*10+c] + b3[c]; m = fmaxf(m, v[c]); }
  float s = 0.f;
  #pragma unroll
  for (int c=0;c<10;c++) s += __expf(v[c]-m);
  float ls = logf(s);
  #pragma unroll
  for (int c=0;c<10;c++) out[n*10+c] = v[c] - m - ls;
}

extern "C" void kernel_launch(void* const* d_in, const int* in_sizes, int n_in,
                              void* d_out, int out_size, void* d_ws, size_t ws_size,
                              hipStream_t stream){
  const float* x   = (const float*)d_in[0];
  const int*  ei   = (const int*)d_in[1];
  const float* W1  = (const float*)d_in[2];
  const float* as1 = (const float*)d_in[3];
  const float* ad1 = (const float*)d_in[4];
  // d_in[5] = b1: cancels under BatchNorm (mean subtraction) -> skipped
  const float* g1  = (const float*)d_in[6];
  const float* be1 = (const float*)d_in[7];
  const float* W2  = (const float*)d_in[8];
  const float* as2 = (const float*)d_in[9];
  const float* ad2 = (const float*)d_in[10];
  // d_in[11] = b2: cancels under BatchNorm -> skipped
  const float* g2  = (const float*)d_in[12];
  const float* be2 = (const float*)d_in[13];
  const float* W3  = (const float*)d_in[14];
  const float* as3 = (const float*)d_in[15];
  const float* ad3 = (const float*)d_in[16];
  const float* b3  = (const float*)d_in[17];
  float* out = (float*)d_out;
  (void)n_in; (void)out_size; (void)ws_size;

  int N = in_sizes[0] / 128;     // 50000
  int E = in_sizes[1] / 2;       // 850000
  const int* src = ei;
  const int* dst = ei + E;

  char* w = (char*)d_ws;
  size_t off = 0;
  auto alloc = [&](size_t bytes) -> void* {
    void* p = w + off;
    off += (bytes + 255) & ~(size_t)255;
    return p;
  };
  bf16* xlb    = (bf16*)alloc((size_t)N*256*2);    // GEMM out (bf16), per layer
  float* gout  = (float*)alloc((size_t)N*256*4);   // GAT out (fp32)
  float* hbuf  = (float*)alloc((size_t)N*256*4);   // BN+ELU out / next GEMM input; also aliases coef
  float* als   = (float*)alloc((size_t)N*8*4);
  float* ald   = (float*)alloc((size_t)N*8*4);
  int* rowptr  = (int*)alloc((size_t)(N+1)*4);
  int* counts  = (int*)alloc((size_t)N*4);
  int* cursor  = (int*)alloc((size_t)N*4);
  int* ssrc    = (int*)alloc((size_t)E*4);
  int* bsums   = (int*)alloc(256*4);
  float* sums  = (float*)alloc(256*4);
  float* sumsq = (float*)alloc(256*4);
  // coef aliases hbuf: live only between k_coef and k_gat2, which never
  // overlaps hbuf's live range (hbuf is consumed by k_gemm before k_coef
  // runs, and rewritten by k_bnapply_elu after k_gat2 completes).
  float* coef  = hbuf;   // E*H*4 <= 27.2 MB <= 51.2 MB

  // ---- CSR by dst (reused for all 3 layers) ----
  hipMemsetAsync(counts, 0, (size_t)N*4, stream);
  hipMemsetAsync(cursor, 0, (size_t)N*4, stream);
  k_hist<<<(E+255)/256, 256, 0, stream>>>(dst, E, counts);
  int nchunks = (N + 1023)/1024;
  k_scan_block<<<nchunks, 1024, 0, stream>>>(counts, N, rowptr, bsums);
  k_scan_sums<<<1, 64, 0, stream>>>(bsums, nchunks);
  k_scan_add<<<(N+1+255)/256, 256, 0, stream>>>(rowptr, bsums, N, E);
  k_scatter<<<(E+255)/256, 256, 0, stream>>>(src, dst, E, rowptr, cursor, ssrc);

  // ---- layer 1: x[N,128] -> h1[N,128] ----
  {
    const int K=128, F=128, H=8;
    dim3 g((N+63)/64, (F+63)/64);
    k_gemm<<<g, 256, 0, stream>>>(x, W1, xlb, N, K, F);
    k_al<<<(N*H+255)/256, 256, 0, stream>>>(xlb, as1, ad1, als, ald, N, H, 16);
    k_coef<8><<<(N*H+255)/256, 256, 0, stream>>>(rowptr, ssrc, als, ald, coef, N);
    k_gat2<8,16,2><<<(N+1)/2, 256, 0, stream>>>(rowptr, ssrc, xlb, coef, gout, N);
    hipMemsetAsync(sums, 0, 256*4, stream);
    hipMemsetAsync(sumsq, 0, 256*4, stream);
    k_bnstats<<<(N+127)/128, F, 0, stream>>>(gout, N, F, sums, sumsq);
    k_bnapply_elu<<<(int)(((size_t)N*F+255)/256), 256, 0, stream>>>(gout, sums, sumsq, g1, be1, hbuf, N, F);
  }
  // ---- layer 2: h1[N,128] -> h2[N,256] ----
  {
    const int K=128, F=256, H=8;
    dim3 g((N+63)/64, (F+63)/64);
    k_gemm<<<g, 256, 0, stream>>>(hbuf, W2, xlb, N, K, F);
    k_al<<<(N*H+255)/256, 256, 0, stream>>>(xlb, as2, ad2, als, ald, N, H, 32);
    k_coef<8><<<(N*H+255)/256, 256, 0, stream>>>(rowptr, ssrc, als, ald, coef, N);
    k_gat2<8,32,1><<<N, 256, 0, stream>>>(rowptr, ssrc, xlb, coef, gout, N);
    hipMemsetAsync(sums, 0, 256*4, stream);
    hipMemsetAsync(sumsq, 0, 256*4, stream);
    k_bnstats<<<(N+127)/128, F, 0, stream>>>(gout, N, F, sums, sumsq);
    k_bnapply_elu<<<(int)(((size_t)N*F+255)/256), 256, 0, stream>>>(gout, sums, sumsq, g2, be2, hbuf, N, F);
  }
  // ---- layer 3: h2[N,256] -> logits[N,10] ----
  {
    const int K=256, F=10, H=1;
    dim3 g((N+63)/64, (F+63)/64);
    k_gemm<<<g, 256, 0, stream>>>(hbuf, W3, xlb, N, K, F);
    k_al<<<(N*H+255)/256, 256, 0, stream>>>(xlb, as3, ad3, als, ald, N, H, 10);
    k_coef<1><<<(N+255)/256, 256, 0, stream>>>(rowptr, ssrc, als, ald, coef, N);
    k_gat2<1,10,32><<<(N+31)/32, 320, 0, stream>>>(rowptr, ssrc, xlb, coef, gout, N);
    k_final<<<(N+255)/256, 256, 0, stream>>>(gout, b3, out, N);
  }
}

// Round 11
// 757.841 us; speedup vs baseline: 1.7405x; 1.1296x over previous
//
#include <hip/hip_runtime.h>
#include <hip/hip_bf16.h>
#include <cstdint>
#include <cstddef>

using bf16 = __hip_bfloat16;
typedef __attribute__((ext_vector_type(8))) short short8;
typedef __attribute__((ext_vector_type(4))) float f32x4;

static __device__ __forceinline__ float lrelu(float x){ return x > 0.f ? x : 0.2f*x; }
static __device__ __forceinline__ float b2f(bf16 v){ return __bfloat162float(v); }

// ---------------- CSR build ----------------
__global__ void k_hist(const int* __restrict__ dst, int E, int* __restrict__ counts){
  int i = blockIdx.x*blockDim.x + threadIdx.x;
  if (i < E) atomicAdd(&counts[dst[i]], 1);
}

__global__ void k_scan_block(const int* __restrict__ counts, int n, int* __restrict__ rowptr, int* __restrict__ bsums){
  __shared__ int buf[1024];
  int tid = threadIdx.x;
  int i = blockIdx.x*1024 + tid;
  int v = (i < n) ? counts[i] : 0;
  buf[tid] = v;
  __syncthreads();
  for (int off = 1; off < 1024; off <<= 1){
    int t = (tid >= off) ? buf[tid-off] : 0;
    __syncthreads();
    buf[tid] += t;
    __syncthreads();
  }
  if (i < n) rowptr[i] = buf[tid] - v;   // local exclusive
  if (tid == 1023) bsums[blockIdx.x] = buf[1023];
}

__global__ void k_scan_sums(int* bsums, int nb){
  if (threadIdx.x == 0 && blockIdx.x == 0){
    int run = 0;
    for (int i = 0; i < nb; i++){ int t = bsums[i]; bsums[i] = run; run += t; }
  }
}

__global__ void k_scan_add(int* __restrict__ rowptr, const int* __restrict__ bsums, int n, int E){
  int i = blockIdx.x*blockDim.x + threadIdx.x;
  if (i < n) rowptr[i] += bsums[i >> 10];
  if (i == n) rowptr[n] = E;
}

__global__ void k_scatter(const int* __restrict__ src, const int* __restrict__ dst, int E,
                          const int* __restrict__ rowptr, int* __restrict__ cursor, int* __restrict__ ssrc){
  int i = blockIdx.x*blockDim.x + threadIdx.x;
  if (i < E){
    int d = dst[i];
    int p = atomicAdd(&cursor[d], 1);
    ssrc[rowptr[d] + p] = src[i];
  }
}

// ---------------- dtype prep ----------------
__global__ void k_cast(const float* __restrict__ in, bf16* __restrict__ outp, int n4){
  int i = blockIdx.x*blockDim.x + threadIdx.x;
  if (i >= n4) return;
  float4 v = reinterpret_cast<const float4*>(in)[i];
  bf16* o = outp + (size_t)i*4;
  o[0] = __float2bfloat16(v.x); o[1] = __float2bfloat16(v.y);
  o[2] = __float2bfloat16(v.z); o[3] = __float2bfloat16(v.w);
}

// Wt[f*K + k] = bf16(W[k*F + f])
__global__ void k_wtrans(const float* __restrict__ W, bf16* __restrict__ Wt, int K, int F){
  int i = blockIdx.x*blockDim.x + threadIdx.x;
  if (i >= K*F) return;
  int k = i / F, f = i - k*F;
  Wt[(size_t)f*K + k] = __float2bfloat16(W[i]);
}

// ---------------- MFMA bf16 GEMM: Y[N,F](bf16) = A[N,K](bf16) @ Wt[FPAD,K]^T ----------------
// block: 256 threads = 4 waves; wave w owns rows [bm + w*16, +16); BN = F (A read once).
// Fragment layouts (m89/m91-verified):
//   A-op: lane l holds A[row = l&15][k0 + 8*(l>>4) + j], j=0..7  -> contiguous 16B
//   B-op: lane l holds B[k0 + 8*(l>>4) + j][col = l&15] = Wt[col][k...]  -> contiguous 16B
//   C/D : col = lane&15, row = (lane>>4)*4 + reg
template<int K, int F, int FPAD>
__global__ __launch_bounds__(256) void k_gemm_mfma(const bf16* __restrict__ A, const bf16* __restrict__ Wt,
                                                   bf16* __restrict__ Y, int N){
  const int NT = FPAD/16;
  int w = threadIdx.x >> 6;       // wave 0..3
  int l = threadIdx.x & 63;       // lane
  int bm = blockIdx.x*64 + w*16;
  int arow = bm + (l & 15);
  int arowc = min(arow, N-1);
  int koff = 8*(l >> 4);
  f32x4 acc[NT];
  #pragma unroll
  for (int t = 0; t < NT; t++) acc[t] = f32x4{0.f,0.f,0.f,0.f};
  const bf16* ap = A + (size_t)arowc*K + koff;
  const bf16* bp = Wt + (size_t)(l & 15)*K + koff;
  for (int k0 = 0; k0 < K; k0 += 32){
    short8 a = *reinterpret_cast<const short8*>(ap + k0);
    #pragma unroll
    for (int t = 0; t < NT; t++){
      short8 b = *reinterpret_cast<const short8*>(bp + (size_t)t*16*K + k0);
      acc[t] = __builtin_amdgcn_mfma_f32_16x16x32_bf16(a, b, acc[t], 0, 0, 0);
    }
  }
  int orow = bm + ((l >> 4) << 2);
  int ocol = l & 15;
  #pragma unroll
  for (int t = 0; t < NT; t++){
    int c = t*16 + ocol;
    if (c >= F) break;
    #pragma unroll
    for (int jr = 0; jr < 4; jr++){
      int r = orow + jr;
      if (r < N) Y[(size_t)r*F + c] = __float2bfloat16(acc[t][jr]);
    }
  }
}

// ---------------- attention logits per node ----------------
__global__ void k_al(const bf16* __restrict__ xl, const float* __restrict__ asrc, const float* __restrict__ adst,
                     float* __restrict__ als, float* __restrict__ ald, int N, int H, int C){
  int i = blockIdx.x*blockDim.x + threadIdx.x;
  if (i >= N*H) return;
  int h = i % H;
  const bf16* row = xl + (size_t)(i/H)*H*C + (size_t)h*C;
  float s = 0.f, d = 0.f;
  for (int c = 0; c < C; c++){ float v = b2f(row[c]); s += v*asrc[h*C+c]; d += v*adst[h*C+c]; }
  als[i] = s; ald[i] = d;
}

// ---------------- softmax coefficients per (dst node, head), CSR-ordered ----------------
template<int H>
__global__ void k_coef(const int* __restrict__ rowptr, const int* __restrict__ ssrc,
                       const float* __restrict__ als, const float* __restrict__ ald,
                       float* __restrict__ coef, int N){
  int i = blockIdx.x*blockDim.x + threadIdx.x;
  if (i >= N*H) return;
  int node = i / H;
  int h = i - node*H;
  int beg = rowptr[node], end = rowptr[node+1];
  float ad = ald[i];
  float m = -1e30f;
  int p = beg;
  for (; p + 4 <= end; p += 4){
    int s0=ssrc[p], s1=ssrc[p+1], s2=ssrc[p+2], s3=ssrc[p+3];
    float a0 = lrelu(als[s0*H + h] + ad);
    float a1 = lrelu(als[s1*H + h] + ad);
    float a2 = lrelu(als[s2*H + h] + ad);
    float a3 = lrelu(als[s3*H + h] + ad);
    coef[(size_t)(p+0)*H + h] = a0;
    coef[(size_t)(p+1)*H + h] = a1;
    coef[(size_t)(p+2)*H + h] = a2;
    coef[(size_t)(p+3)*H + h] = a3;
    m = fmaxf(m, fmaxf(fmaxf(a0,a1), fmaxf(a2,a3)));
  }
  for (; p < end; p++){
    float a = lrelu(als[ssrc[p]*H + h] + ad);
    coef[(size_t)p*H + h] = a;
    m = fmaxf(m, a);
  }
  float s = 0.f;
  for (p = beg; p < end; p++){
    float w = __expf(coef[(size_t)p*H + h] - m);
    coef[(size_t)p*H + h] = w;
    s += w;
  }
  float inv = 1.f / (s + 1e-16f);
  for (p = beg; p < end; p++) coef[(size_t)p*H + h] *= inv;
}

// ---------------- GAT aggregation: pure gather-FMA, unrolled x4 for MLP ----------------
template<int H, int C, int NPB>
__global__ void k_gat2(const int* __restrict__ rowptr, const int* __restrict__ ssrc,
                       const bf16* __restrict__ xl, const float* __restrict__ coef,
                       float* __restrict__ out, int N){
  const int F = H*C;
  int tid = threadIdx.x;
  int node = blockIdx.x*NPB + tid/F;
  int lt = tid - (tid/F)*F;
  if (node >= N) return;
  int h = lt / C;
  int beg = rowptr[node], end = rowptr[node+1];
  const float* cof = coef + h;
  const bf16* xlp = xl + lt;
  float acc = 0.f;
  int p = beg;
  for (; p + 4 <= end; p += 4){
    int s0=ssrc[p], s1=ssrc[p+1], s2=ssrc[p+2], s3=ssrc[p+3];
    float c0 = cof[(size_t)(p+0)*H];
    float c1 = cof[(size_t)(p+1)*H];
    float c2 = cof[(size_t)(p+2)*H];
    float c3 = cof[(size_t)(p+3)*H];
    float v0 = b2f(xlp[(size_t)s0*F]);
    float v1 = b2f(xlp[(size_t)s1*F]);
    float v2 = b2f(xlp[(size_t)s2*F]);
    float v3 = b2f(xlp[(size_t)s3*F]);
    acc += c0*v0;
    acc += c1*v1;
    acc += c2*v2;
    acc += c3*v3;
  }
  for (; p < end; p++){
    int si = ssrc[p];
    acc += cof[(size_t)p*H] * b2f(xlp[(size_t)si*F]);
  }
  out[(size_t)node*F + lt] = acc;
}

// ---------------- BatchNorm ----------------
__global__ void k_bnstats(const float* __restrict__ x, int N, int F, float* __restrict__ sums, float* __restrict__ sumsq){
  int f = threadIdx.x;
  if (f >= F) return;
  int r0 = blockIdx.x*128;
  int r1 = min(r0+128, N);
  float s=0.f, s2=0.f;
  for (int r=r0; r<r1; r++){ float v = x[(size_t)r*F + f]; s += v; s2 += v*v; }
  atomicAdd(&sums[f], s);
  atomicAdd(&sumsq[f], s2);
}

// BN + ELU, output bf16 (feeds the next MFMA GEMM directly)
__global__ void k_bnapply_elu(const float* __restrict__ x, const float* __restrict__ sums, const float* __restrict__ sumsq,
                              const float* __restrict__ g, const float* __restrict__ beta,
                              bf16* __restrict__ y, int N, int F){
  int i = blockIdx.x*blockDim.x + threadIdx.x;
  if (i >= N*F) return;
  int f = i % F;
  float mu = sums[f] / (float)N;
  float var = sumsq[f] / (float)N - mu*mu;
  float inv = rsqrtf(var + 1e-5f);
  float v = (x[i]-mu)*inv*g[f] + beta[f];
  v = v > 0.f ? v : (__expf(v) - 1.f);
  y[i] = __float2bfloat16(v);
}

// ---------------- final: +bias, log_softmax over 10 classes ----------------
__global__ void k_final(const float* __restrict__ x, const float* __restrict__ b3, float* __restrict__ out, int N){
  int n = blockIdx.x*blockDim.x + threadIdx.x;
  if (n >= N) return;
  float v[10];
  float m = -1e30f;
  #pragma unroll
  for (int c=0;c<10;c++){ v[c] = x[n*10+c] + b3[c]; m = fmaxf(m, v[c]); }
  float s = 0.f;
  #pragma unroll
  for (int c=0;c<10;c++) s += __expf(v[c]-m);
  float ls = logf(s);
  #pragma unroll
  for (int c=0;c<10;c++) out[n*10+c] = v[c] - m - ls;
}

extern "C" void kernel_launch(void* const* d_in, const int* in_sizes, int n_in,
                              void* d_out, int out_size, void* d_ws, size_t ws_size,
                              hipStream_t stream){
  const float* x   = (const float*)d_in[0];
  const int*  ei   = (const int*)d_in[1];
  const float* W1  = (const float*)d_in[2];
  const float* as1 = (const float*)d_in[3];
  const float* ad1 = (const float*)d_in[4];
  // d_in[5] = b1: cancels under BatchNorm (mean subtraction) -> skipped
  const float* g1  = (const float*)d_in[6];
  const float* be1 = (const float*)d_in[7];
  const float* W2  = (const float*)d_in[8];
  const float* as2 = (const float*)d_in[9];
  const float* ad2 = (const float*)d_in[10];
  // d_in[11] = b2: cancels under BatchNorm -> skipped
  const float* g2  = (const float*)d_in[12];
  const float* be2 = (const float*)d_in[13];
  const float* W3  = (const float*)d_in[14];
  const float* as3 = (const float*)d_in[15];
  const float* ad3 = (const float*)d_in[16];
  const float* b3  = (const float*)d_in[17];
  float* out = (float*)d_out;
  (void)n_in; (void)out_size; (void)ws_size;

  int N = in_sizes[0] / 128;     // 50000
  int E = in_sizes[1] / 2;       // 850000
  const int* src = ei;
  const int* dst = ei + E;

  char* w = (char*)d_ws;
  size_t off = 0;
  auto alloc = [&](size_t bytes) -> void* {
    void* p = w + off;
    off += (bytes + 255) & ~(size_t)255;
    return p;
  };
  bf16* xlb    = (bf16*)alloc((size_t)N*256*2);    // GEMM out (bf16), per layer
  float* gout  = (float*)alloc((size_t)N*256*4);   // GAT out (fp32)
  bf16*  hb    = (bf16*)alloc((size_t)N*256*2);    // BN+ELU out (bf16) = next GEMM input
  float* coef  = (float*)alloc((size_t)E*8*4);     // softmax coefs, CSR-ordered
  bf16*  xb    = (bf16*)alloc((size_t)N*128*2);    // x cast to bf16
  bf16*  Wt1   = (bf16*)alloc((size_t)128*128*2);  // W^T bf16
  bf16*  Wt2   = (bf16*)alloc((size_t)256*128*2);
  bf16*  Wt3   = (bf16*)alloc((size_t)16*256*2);   // padded to 16 cols
  float* als   = (float*)alloc((size_t)N*8*4);
  float* ald   = (float*)alloc((size_t)N*8*4);
  int* rowptr  = (int*)alloc((size_t)(N+1)*4);
  int* counts  = (int*)alloc((size_t)N*4);
  int* cursor  = (int*)alloc((size_t)N*4);
  int* ssrc    = (int*)alloc((size_t)E*4);
  int* bsums   = (int*)alloc(256*4);
  float* sums  = (float*)alloc(256*4);
  float* sumsq = (float*)alloc(256*4);

  // ---- CSR by dst (reused for all 3 layers) ----
  hipMemsetAsync(counts, 0, (size_t)N*4, stream);
  hipMemsetAsync(cursor, 0, (size_t)N*4, stream);
  k_hist<<<(E+255)/256, 256, 0, stream>>>(dst, E, counts);
  int nchunks = (N + 1023)/1024;
  k_scan_block<<<nchunks, 1024, 0, stream>>>(counts, N, rowptr, bsums);
  k_scan_sums<<<1, 64, 0, stream>>>(bsums, nchunks);
  k_scan_add<<<(N+1+255)/256, 256, 0, stream>>>(rowptr, bsums, N, E);
  k_scatter<<<(E+255)/256, 256, 0, stream>>>(src, dst, E, rowptr, cursor, ssrc);

  // ---- dtype prep ----
  k_cast<<<((N*128/4)+255)/256, 256, 0, stream>>>(x, xb, N*128/4);
  k_wtrans<<<(128*128+255)/256, 256, 0, stream>>>(W1, Wt1, 128, 128);
  k_wtrans<<<(128*256+255)/256, 256, 0, stream>>>(W2, Wt2, 128, 256);
  hipMemsetAsync(Wt3, 0, (size_t)16*256*2, stream);
  k_wtrans<<<(256*10+255)/256, 256, 0, stream>>>(W3, Wt3, 256, 10);

  int gblk = (N + 63)/64;

  // ---- layer 1: x[N,128] -> h1[N,128] ----
  {
    const int F=128, H=8;
    k_gemm_mfma<128,128,128><<<gblk, 256, 0, stream>>>(xb, Wt1, xlb, N);
    k_al<<<(N*H+255)/256, 256, 0, stream>>>(xlb, as1, ad1, als, ald, N, H, 16);
    k_coef<8><<<(N*H+255)/256, 256, 0, stream>>>(rowptr, ssrc, als, ald, coef, N);
    k_gat2<8,16,2><<<(N+1)/2, 256, 0, stream>>>(rowptr, ssrc, xlb, coef, gout, N);
    hipMemsetAsync(sums, 0, 256*4, stream);
    hipMemsetAsync(sumsq, 0, 256*4, stream);
    k_bnstats<<<(N+127)/128, F, 0, stream>>>(gout, N, F, sums, sumsq);
    k_bnapply_elu<<<(int)(((size_t)N*F+255)/256), 256, 0, stream>>>(gout, sums, sumsq, g1, be1, hb, N, F);
  }
  // ---- layer 2: h1[N,128] -> h2[N,256] ----
  {
    const int F=256, H=8;
    k_gemm_mfma<128,256,256><<<gblk, 256, 0, stream>>>(hb, Wt2, xlb, N);
    k_al<<<(N*H+255)/256, 256, 0, stream>>>(xlb, as2, ad2, als, ald, N, H, 32);
    k_coef<8><<<(N*H+255)/256, 256, 0, stream>>>(rowptr, ssrc, als, ald, coef, N);
    k_gat2<8,32,1><<<N, 256, 0, stream>>>(rowptr, ssrc, xlb, coef, gout, N);
    hipMemsetAsync(sums, 0, 256*4, stream);
    hipMemsetAsync(sumsq, 0, 256*4, stream);
    k_bnstats<<<(N+127)/128, F, 0, stream>>>(gout, N, F, sums, sumsq);
    k_bnapply_elu<<<(int)(((size_t)N*F+255)/256), 256, 0, stream>>>(gout, sums, sumsq, g2, be2, hb, N, F);
  }
  // ---- layer 3: h2[N,256] -> logits[N,10] ----
  {
    const int H=1;
    k_gemm_mfma<256,10,16><<<gblk, 256, 0, stream>>>(hb, Wt3, xlb, N);
    k_al<<<(N*H+255)/256, 256, 0, stream>>>(xlb, as3, ad3, als, ald, N, H, 10);
    k_coef<1><<<(N+255)/256, 256, 0, stream>>>(rowptr, ssrc, als, ald, coef, N);
    k_gat2<1,10,32><<<(N+31)/32, 320, 0, stream>>>(rowptr, ssrc, xlb, coef, gout, N);
    k_final<<<(N+255)/256, 256, 0, stream>>>(gout, b3, out, N);
  }
}

// Round 13
// 714.215 us; speedup vs baseline: 1.8468x; 1.0611x over previous
//
#include <hip/hip_runtime.h>
#include <hip/hip_bf16.h>
#include <cstdint>
#include <cstddef>

using bf16 = __hip_bfloat16;
typedef __attribute__((ext_vector_type(8))) short short8;
typedef __attribute__((ext_vector_type(4))) float f32x4;

static __device__ __forceinline__ float lrelu(float x){ return x > 0.f ? x : 0.2f*x; }
static __device__ __forceinline__ float b2f(bf16 v){ return __bfloat162float(v); }

// ---------------- CSR build ----------------
__global__ void k_hist(const int* __restrict__ dst, int E, int* __restrict__ counts){
  int i = blockIdx.x*blockDim.x + threadIdx.x;
  if (i < E) atomicAdd(&counts[dst[i]], 1);
}

__global__ void k_scan_block(const int* __restrict__ counts, int n, int* __restrict__ rowptr, int* __restrict__ bsums){
  __shared__ int buf[1024];
  int tid = threadIdx.x;
  int i = blockIdx.x*1024 + tid;
  int v = (i < n) ? counts[i] : 0;
  buf[tid] = v;
  __syncthreads();
  for (int off = 1; off < 1024; off <<= 1){
    int t = (tid >= off) ? buf[tid-off] : 0;
    __syncthreads();
    buf[tid] += t;
    __syncthreads();
  }
  if (i < n) rowptr[i] = buf[tid] - v;   // local exclusive
  if (tid == 1023) bsums[blockIdx.x] = buf[1023];
}

__global__ void k_scan_sums(int* bsums, int nb){
  if (threadIdx.x == 0 && blockIdx.x == 0){
    int run = 0;
    for (int i = 0; i < nb; i++){ int t = bsums[i]; bsums[i] = run; run += t; }
  }
}

__global__ void k_scan_add(int* __restrict__ rowptr, const int* __restrict__ bsums, int n, int E){
  int i = blockIdx.x*blockDim.x + threadIdx.x;
  if (i < n) rowptr[i] += bsums[i >> 10];
  if (i == n) rowptr[n] = E;
}

__global__ void k_scatter(const int* __restrict__ src, const int* __restrict__ dst, int E,
                          const int* __restrict__ rowptr, int* __restrict__ cursor, int* __restrict__ ssrc){
  int i = blockIdx.x*blockDim.x + threadIdx.x;
  if (i < E){
    int d = dst[i];
    int p = atomicAdd(&cursor[d], 1);
    ssrc[rowptr[d] + p] = src[i];
  }
}

// ---------------- dtype prep ----------------
__global__ void k_cast(const float* __restrict__ in, bf16* __restrict__ outp, int n4){
  int i = blockIdx.x*blockDim.x + threadIdx.x;
  if (i >= n4) return;
  float4 v = reinterpret_cast<const float4*>(in)[i];
  bf16* o = outp + (size_t)i*4;
  o[0] = __float2bfloat16(v.x); o[1] = __float2bfloat16(v.y);
  o[2] = __float2bfloat16(v.z); o[3] = __float2bfloat16(v.w);
}

// Wt[f*K + k] = bf16(W[k*F + f])
__global__ void k_wtrans(const float* __restrict__ W, bf16* __restrict__ Wt, int K, int F){
  int i = blockIdx.x*blockDim.x + threadIdx.x;
  if (i >= K*F) return;
  int k = i / F, f = i - k*F;
  Wt[(size_t)f*K + k] = __float2bfloat16(W[i]);
}

// ---------------- MFMA bf16 GEMM: Y[N,F](bf16) = A[N,K](bf16) @ Wt[FPAD,K]^T ----------------
template<int K, int F, int FPAD>
__global__ __launch_bounds__(256) void k_gemm_mfma(const bf16* __restrict__ A, const bf16* __restrict__ Wt,
                                                   bf16* __restrict__ Y, int N){
  const int NT = FPAD/16;
  int w = threadIdx.x >> 6;       // wave 0..3
  int l = threadIdx.x & 63;       // lane
  int bm = blockIdx.x*64 + w*16;
  int arow = bm + (l & 15);
  int arowc = min(arow, N-1);
  int koff = 8*(l >> 4);
  f32x4 acc[NT];
  #pragma unroll
  for (int t = 0; t < NT; t++) acc[t] = f32x4{0.f,0.f,0.f,0.f};
  const bf16* ap = A + (size_t)arowc*K + koff;
  const bf16* bp = Wt + (size_t)(l & 15)*K + koff;
  for (int k0 = 0; k0 < K; k0 += 32){
    short8 a = *reinterpret_cast<const short8*>(ap + k0);
    #pragma unroll
    for (int t = 0; t < NT; t++){
      short8 b = *reinterpret_cast<const short8*>(bp + (size_t)t*16*K + k0);
      acc[t] = __builtin_amdgcn_mfma_f32_16x16x32_bf16(a, b, acc[t], 0, 0, 0);
    }
  }
  int orow = bm + ((l >> 4) << 2);
  int ocol = l & 15;
  #pragma unroll
  for (int t = 0; t < NT; t++){
    int c = t*16 + ocol;
    if (c >= F) break;
    #pragma unroll
    for (int jr = 0; jr < 4; jr++){
      int r = orow + jr;
      if (r < N) Y[(size_t)r*F + c] = __float2bfloat16(acc[t][jr]);
    }
  }
}

// ---------------- attention logits per node ----------------
__global__ void k_al(const bf16* __restrict__ xl, const float* __restrict__ asrc, const float* __restrict__ adst,
                     float* __restrict__ als, float* __restrict__ ald, int N, int H, int C){
  int i = blockIdx.x*blockDim.x + threadIdx.x;
  if (i >= N*H) return;
  int h = i % H;
  const bf16* row = xl + (size_t)(i/H)*H*C + (size_t)h*C;
  float s = 0.f, d = 0.f;
  for (int c = 0; c < C; c++){ float v = b2f(row[c]); s += v*asrc[h*C+c]; d += v*adst[h*C+c]; }
  als[i] = s; ald[i] = d;
}

// ---------------- softmax: 2-gather passes, write UNNORMALIZED w once + inv[N,H] ----------------
// pass 1: compute max (recompute logits from als — als is ~1.6MB, L2-resident, cheaper than spilling)
// pass 2: w = exp(a-m), store; s += w. inv stored separately, applied in k_gat2.
template<int H>
__global__ void k_coef(const int* __restrict__ rowptr, const int* __restrict__ ssrc,
                       const float* __restrict__ als, const float* __restrict__ ald,
                       float* __restrict__ coef, float* __restrict__ invs, int N){
  int i = blockIdx.x*blockDim.x + threadIdx.x;
  if (i >= N*H) return;
  int node = i / H;
  int h = i - node*H;
  int beg = rowptr[node], end = rowptr[node+1];
  float ad = ald[i];
  float m = -1e30f;
  int p = beg;
  for (; p + 4 <= end; p += 4){
    int s0=ssrc[p], s1=ssrc[p+1], s2=ssrc[p+2], s3=ssrc[p+3];
    float a0 = lrelu(als[s0*H + h] + ad);
    float a1 = lrelu(als[s1*H + h] + ad);
    float a2 = lrelu(als[s2*H + h] + ad);
    float a3 = lrelu(als[s3*H + h] + ad);
    m = fmaxf(m, fmaxf(fmaxf(a0,a1), fmaxf(a2,a3)));
  }
  for (; p < end; p++) m = fmaxf(m, lrelu(als[ssrc[p]*H + h] + ad));
  float s = 0.f;
  p = beg;
  for (; p + 4 <= end; p += 4){
    int s0=ssrc[p], s1=ssrc[p+1], s2=ssrc[p+2], s3=ssrc[p+3];
    float w0 = __expf(lrelu(als[s0*H + h] + ad) - m);
    float w1 = __expf(lrelu(als[s1*H + h] + ad) - m);
    float w2 = __expf(lrelu(als[s2*H + h] + ad) - m);
    float w3 = __expf(lrelu(als[s3*H + h] + ad) - m);
    coef[(size_t)(p+0)*H + h] = w0;
    coef[(size_t)(p+1)*H + h] = w1;
    coef[(size_t)(p+2)*H + h] = w2;
    coef[(size_t)(p+3)*H + h] = w3;
    s += w0 + w1 + w2 + w3;
  }
  for (; p < end; p++){
    float w = __expf(lrelu(als[ssrc[p]*H + h] + ad) - m);
    coef[(size_t)p*H + h] = w;
    s += w;
  }
  invs[i] = 1.f / (s + 1e-16f);
}

// ---------------- GAT aggregation: gather-FMA, unrolled x8 for MLP; normalize at end ----------------
template<int H, int C, int NPB>
__global__ void k_gat2(const int* __restrict__ rowptr, const int* __restrict__ ssrc,
                       const bf16* __restrict__ xl, const float* __restrict__ coef,
                       const float* __restrict__ invs, float* __restrict__ out, int N){
  const int F = H*C;
  int tid = threadIdx.x;
  int node = blockIdx.x*NPB + tid/F;
  int lt = tid - (tid/F)*F;
  if (node >= N) return;
  int h = lt / C;
  int beg = rowptr[node], end = rowptr[node+1];
  const float* cof = coef + h;
  const bf16* xlp = xl + lt;
  float acc = 0.f;
  int p = beg;
  for (; p + 8 <= end; p += 8){
    int s0=ssrc[p],   s1=ssrc[p+1], s2=ssrc[p+2], s3=ssrc[p+3];
    int s4=ssrc[p+4], s5=ssrc[p+5], s6=ssrc[p+6], s7=ssrc[p+7];
    float c0 = cof[(size_t)(p+0)*H];
    float c1 = cof[(size_t)(p+1)*H];
    float c2 = cof[(size_t)(p+2)*H];
    float c3 = cof[(size_t)(p+3)*H];
    float c4 = cof[(size_t)(p+4)*H];
    float c5 = cof[(size_t)(p+5)*H];
    float c6 = cof[(size_t)(p+6)*H];
    float c7 = cof[(size_t)(p+7)*H];
    float v0 = b2f(xlp[(size_t)s0*F]);
    float v1 = b2f(xlp[(size_t)s1*F]);
    float v2 = b2f(xlp[(size_t)s2*F]);
    float v3 = b2f(xlp[(size_t)s3*F]);
    float v4 = b2f(xlp[(size_t)s4*F]);
    float v5 = b2f(xlp[(size_t)s5*F]);
    float v6 = b2f(xlp[(size_t)s6*F]);
    float v7 = b2f(xlp[(size_t)s7*F]);
    acc += c0*v0; acc += c1*v1; acc += c2*v2; acc += c3*v3;
    acc += c4*v4; acc += c5*v5; acc += c6*v6; acc += c7*v7;
  }
  for (; p + 4 <= end; p += 4){
    int s0=ssrc[p], s1=ssrc[p+1], s2=ssrc[p+2], s3=ssrc[p+3];
    float c0 = cof[(size_t)(p+0)*H];
    float c1 = cof[(size_t)(p+1)*H];
    float c2 = cof[(size_t)(p+2)*H];
    float c3 = cof[(size_t)(p+3)*H];
    float v0 = b2f(xlp[(size_t)s0*F]);
    float v1 = b2f(xlp[(size_t)s1*F]);
    float v2 = b2f(xlp[(size_t)s2*F]);
    float v3 = b2f(xlp[(size_t)s3*F]);
    acc += c0*v0; acc += c1*v1; acc += c2*v2; acc += c3*v3;
  }
  for (; p < end; p++){
    int si = ssrc[p];
    acc += cof[(size_t)p*H] * b2f(xlp[(size_t)si*F]);
  }
  out[(size_t)node*F + lt] = acc * invs[node*H + h];
}

// ---------------- BatchNorm ----------------
__global__ void k_bnstats(const float* __restrict__ x, int N, int F, float* __restrict__ sums, float* __restrict__ sumsq){
  int f = threadIdx.x;
  if (f >= F) return;
  int r0 = blockIdx.x*128;
  int r1 = min(r0+128, N);
  float s=0.f, s2=0.f;
  for (int r=r0; r<r1; r++){ float v = x[(size_t)r*F + f]; s += v; s2 += v*v; }
  atomicAdd(&sums[f], s);
  atomicAdd(&sumsq[f], s2);
}

// BN + ELU, output bf16 (feeds the next MFMA GEMM directly)
__global__ void k_bnapply_elu(const float* __restrict__ x, const float* __restrict__ sums, const float* __restrict__ sumsq,
                              const float* __restrict__ g, const float* __restrict__ beta,
                              bf16* __restrict__ y, int N, int F){
  int i = blockIdx.x*blockDim.x + threadIdx.x;
  if (i >= N*F) return;
  int f = i % F;
  float mu = sums[f] / (float)N;
  float var = sumsq[f] / (float)N - mu*mu;
  float inv = rsqrtf(var + 1e-5f);
  float v = (x[i]-mu)*inv*g[f] + beta[f];
  v = v > 0.f ? v : (__expf(v) - 1.f);
  y[i] = __float2bfloat16(v);
}

// ---------------- final: +bias, log_softmax over 10 classes ----------------
__global__ void k_final(const float* __restrict__ x, const float* __restrict__ b3, float* __restrict__ out, int N){
  int n = blockIdx.x*blockDim.x + threadIdx.x;
  if (n >= N) return;
  float v[10];
  float m = -1e30f;
  #pragma unroll
  for (int c=0;c<10;c++){ v[c] = x[n*10+c] + b3[c]; m = fmaxf(m, v[c]); }
  float s = 0.f;
  #pragma unroll
  for (int c=0;c<10;c++) s += __expf(v[c]-m);
  float ls = logf(s);
  #pragma unroll
  for (int c=0;c<10;c++) out[n*10+c] = v[c] - m - ls;
}

extern "C" void kernel_launch(void* const* d_in, const int* in_sizes, int n_in,
                              void* d_out, int out_size, void* d_ws, size_t ws_size,
                              hipStream_t stream){
  const float* x   = (const float*)d_in[0];
  const int*  ei   = (const int*)d_in[1];
  const float* W1  = (const float*)d_in[2];
  const float* as1 = (const float*)d_in[3];
  const float* ad1 = (const float*)d_in[4];
  // d_in[5] = b1: cancels under BatchNorm (mean subtraction) -> skipped
  const float* g1  = (const float*)d_in[6];
  const float* be1 = (const float*)d_in[7];
  const float* W2  = (const float*)d_in[8];
  const float* as2 = (const float*)d_in[9];
  const float* ad2 = (const float*)d_in[10];
  // d_in[11] = b2: cancels under BatchNorm -> skipped
  const float* g2  = (const float*)d_in[12];
  const float* be2 = (const float*)d_in[13];
  const float* W3  = (const float*)d_in[14];
  const float* as3 = (const float*)d_in[15];
  const float* ad3 = (const float*)d_in[16];
  const float* b3  = (const float*)d_in[17];
  float* out = (float*)d_out;
  (void)n_in; (void)out_size; (void)ws_size;

  int N = in_sizes[0] / 128;     // 50000
  int E = in_sizes[1] / 2;       // 850000
  const int* src = ei;
  const int* dst = ei + E;

  char* w = (char*)d_ws;
  size_t off = 0;
  auto alloc = [&](size_t bytes) -> void* {
    void* p = w + off;
    off += (bytes + 255) & ~(size_t)255;
    return p;
  };
  bf16* xlb    = (bf16*)alloc((size_t)N*256*2);    // GEMM out (bf16), per layer
  float* gout  = (float*)alloc((size_t)N*256*4);   // GAT out (fp32)
  bf16*  hb    = (bf16*)alloc((size_t)N*256*2);    // BN+ELU out (bf16) = next GEMM input
  float* coef  = (float*)alloc((size_t)E*8*4);     // softmax weights (unnormalized), CSR-ordered
  bf16*  xb    = (bf16*)alloc((size_t)N*128*2);    // x cast to bf16
  bf16*  Wt1   = (bf16*)alloc((size_t)128*128*2);  // W^T bf16
  bf16*  Wt2   = (bf16*)alloc((size_t)256*128*2);
  bf16*  Wt3   = (bf16*)alloc((size_t)16*256*2);   // padded to 16 cols
  float* als   = (float*)alloc((size_t)N*8*4);
  float* ald   = (float*)alloc((size_t)N*8*4);
  float* invs  = (float*)alloc((size_t)N*8*4);
  int* rowptr  = (int*)alloc((size_t)(N+1)*4);
  int* counts  = (int*)alloc((size_t)N*4);
  int* cursor  = (int*)alloc((size_t)N*4);
  int* ssrc    = (int*)alloc((size_t)E*4);
  int* bsums   = (int*)alloc(256*4);
  float* sums  = (float*)alloc(256*4);
  float* sumsq = (float*)alloc(256*4);

  // ---- CSR by dst (reused for all 3 layers) ----
  hipMemsetAsync(counts, 0, (size_t)N*4, stream);
  hipMemsetAsync(cursor, 0, (size_t)N*4, stream);
  k_hist<<<(E+255)/256, 256, 0, stream>>>(dst, E, counts);
  int nchunks = (N + 1023)/1024;
  k_scan_block<<<nchunks, 1024, 0, stream>>>(counts, N, rowptr, bsums);
  k_scan_sums<<<1, 64, 0, stream>>>(bsums, nchunks);
  k_scan_add<<<(N+1+255)/256, 256, 0, stream>>>(rowptr, bsums, N, E);
  k_scatter<<<(E+255)/256, 256, 0, stream>>>(src, dst, E, rowptr, cursor, ssrc);

  // ---- dtype prep ----
  k_cast<<<((N*128/4)+255)/256, 256, 0, stream>>>(x, xb, N*128/4);
  k_wtrans<<<(128*128+255)/256, 256, 0, stream>>>(W1, Wt1, 128, 128);
  k_wtrans<<<(128*256+255)/256, 256, 0, stream>>>(W2, Wt2, 128, 256);
  hipMemsetAsync(Wt3, 0, (size_t)16*256*2, stream);
  k_wtrans<<<(256*10+255)/256, 256, 0, stream>>>(W3, Wt3, 256, 10);

  int gblk = (N + 63)/64;

  // ---- layer 1: x[N,128] -> h1[N,128] ----
  {
    const int F=128, H=8;
    k_gemm_mfma<128,128,128><<<gblk, 256, 0, stream>>>(xb, Wt1, xlb, N);
    k_al<<<(N*H+255)/256, 256, 0, stream>>>(xlb, as1, ad1, als, ald, N, H, 16);
    k_coef<8><<<(N*H+255)/256, 256, 0, stream>>>(rowptr, ssrc, als, ald, coef, invs, N);
    k_gat2<8,16,2><<<(N+1)/2, 256, 0, stream>>>(rowptr, ssrc, xlb, coef, invs, gout, N);
    hipMemsetAsync(sums, 0, 256*4, stream);
    hipMemsetAsync(sumsq, 0, 256*4, stream);
    k_bnstats<<<(N+127)/128, F, 0, stream>>>(gout, N, F, sums, sumsq);
    k_bnapply_elu<<<(int)(((size_t)N*F+255)/256), 256, 0, stream>>>(gout, sums, sumsq, g1, be1, hb, N, F);
  }
  // ---- layer 2: h1[N,128] -> h2[N,256] ----
  {
    const int F=256, H=8;
    k_gemm_mfma<128,256,256><<<gblk, 256, 0, stream>>>(hb, Wt2, xlb, N);
    k_al<<<(N*H+255)/256, 256, 0, stream>>>(xlb, as2, ad2, als, ald, N, H, 32);
    k_coef<8><<<(N*H+255)/256, 256, 0, stream>>>(rowptr, ssrc, als, ald, coef, invs, N);
    k_gat2<8,32,1><<<N, 256, 0, stream>>>(rowptr, ssrc, xlb, coef, invs, gout, N);
    hipMemsetAsync(sums, 0, 256*4, stream);
    hipMemsetAsync(sumsq, 0, 256*4, stream);
    k_bnstats<<<(N+127)/128, F, 0, stream>>>(gout, N, F, sums, sumsq);
    k_bnapply_elu<<<(int)(((size_t)N*F+255)/256), 256, 0, stream>>>(gout, sums, sumsq, g2, be2, hb, N, F);
  }
  // ---- layer 3: h2[N,256] -> logits[N,10] ----
  {
    const int H=1;
    k_gemm_mfma<256,10,16><<<gblk, 256, 0, stream>>>(hb, Wt3, xlb, N);
    k_al<<<(N*H+255)/256, 256, 0, stream>>>(xlb, as3, ad3, als, ald, N, H, 10);
    k_coef<1><<<(N+255)/256, 256, 0, stream>>>(rowptr, ssrc, als, ald, coef, invs, N);
    k_gat2<1,10,32><<<(N+31)/32, 320, 0, stream>>>(rowptr, ssrc, xlb, coef, invs, gout, N);
    k_final<<<(N+255)/256, 256, 0, stream>>>(gout, b3, out, N);
  }
}

// Round 14
// 646.248 us; speedup vs baseline: 2.0410x; 1.1052x over previous
//
#include <hip/hip_runtime.h>
#include <hip/hip_bf16.h>
#include <cstdint>
#include <cstddef>

using bf16 = __hip_bfloat16;
typedef __attribute__((ext_vector_type(8))) short short8;
typedef __attribute__((ext_vector_type(4))) float f32x4;

static __device__ __forceinline__ float lrelu(float x){ return x > 0.f ? x : 0.2f*x; }
static __device__ __forceinline__ float b2f(bf16 v){ return __bfloat162float(v); }
static __device__ __forceinline__ float u2f(unsigned short u){ return __uint_as_float(((unsigned)u) << 16); }

// ---------------- CSR build ----------------
__global__ void k_hist(const int* __restrict__ dst, int E, int* __restrict__ counts){
  int i = blockIdx.x*blockDim.x + threadIdx.x;
  if (i < E) atomicAdd(&counts[dst[i]], 1);
}

__global__ void k_scan_block(const int* __restrict__ counts, int n, int* __restrict__ rowptr, int* __restrict__ bsums){
  __shared__ int buf[1024];
  int tid = threadIdx.x;
  int i = blockIdx.x*1024 + tid;
  int v = (i < n) ? counts[i] : 0;
  buf[tid] = v;
  __syncthreads();
  for (int off = 1; off < 1024; off <<= 1){
    int t = (tid >= off) ? buf[tid-off] : 0;
    __syncthreads();
    buf[tid] += t;
    __syncthreads();
  }
  if (i < n) rowptr[i] = buf[tid] - v;   // local exclusive
  if (tid == 1023) bsums[blockIdx.x] = buf[1023];
}

__global__ void k_scan_sums(int* bsums, int nb){
  if (threadIdx.x == 0 && blockIdx.x == 0){
    int run = 0;
    for (int i = 0; i < nb; i++){ int t = bsums[i]; bsums[i] = run; run += t; }
  }
}

__global__ void k_scan_add(int* __restrict__ rowptr, const int* __restrict__ bsums, int n, int E){
  int i = blockIdx.x*blockDim.x + threadIdx.x;
  if (i < n) rowptr[i] += bsums[i >> 10];
  if (i == n) rowptr[n] = E;
}

__global__ void k_scatter(const int* __restrict__ src, const int* __restrict__ dst, int E,
                          const int* __restrict__ rowptr, int* __restrict__ cursor, int* __restrict__ ssrc){
  int i = blockIdx.x*blockDim.x + threadIdx.x;
  if (i < E){
    int d = dst[i];
    int p = atomicAdd(&cursor[d], 1);
    ssrc[rowptr[d] + p] = src[i];
  }
}

// ---------------- dtype prep ----------------
__global__ void k_cast(const float* __restrict__ in, bf16* __restrict__ outp, int n4){
  int i = blockIdx.x*blockDim.x + threadIdx.x;
  if (i >= n4) return;
  float4 v = reinterpret_cast<const float4*>(in)[i];
  bf16* o = outp + (size_t)i*4;
  o[0] = __float2bfloat16(v.x); o[1] = __float2bfloat16(v.y);
  o[2] = __float2bfloat16(v.z); o[3] = __float2bfloat16(v.w);
}

// Wt[f*K + k] = bf16(W[k*F + f])
__global__ void k_wtrans(const float* __restrict__ W, bf16* __restrict__ Wt, int K, int F){
  int i = blockIdx.x*blockDim.x + threadIdx.x;
  if (i >= K*F) return;
  int k = i / F, f = i - k*F;
  Wt[(size_t)f*K + k] = __float2bfloat16(W[i]);
}

// ---------------- MFMA bf16 GEMM: Y[N,F](bf16) = A[N,K](bf16) @ Wt[FPAD,K]^T ----------------
template<int K, int F, int FPAD>
__global__ __launch_bounds__(256) void k_gemm_mfma(const bf16* __restrict__ A, const bf16* __restrict__ Wt,
                                                   bf16* __restrict__ Y, int N){
  const int NT = FPAD/16;
  int w = threadIdx.x >> 6;       // wave 0..3
  int l = threadIdx.x & 63;       // lane
  int bm = blockIdx.x*64 + w*16;
  int arow = bm + (l & 15);
  int arowc = min(arow, N-1);
  int koff = 8*(l >> 4);
  f32x4 acc[NT];
  #pragma unroll
  for (int t = 0; t < NT; t++) acc[t] = f32x4{0.f,0.f,0.f,0.f};
  const bf16* ap = A + (size_t)arowc*K + koff;
  const bf16* bp = Wt + (size_t)(l & 15)*K + koff;
  for (int k0 = 0; k0 < K; k0 += 32){
    short8 a = *reinterpret_cast<const short8*>(ap + k0);
    #pragma unroll
    for (int t = 0; t < NT; t++){
      short8 b = *reinterpret_cast<const short8*>(bp + (size_t)t*16*K + k0);
      acc[t] = __builtin_amdgcn_mfma_f32_16x16x32_bf16(a, b, acc[t], 0, 0, 0);
    }
  }
  int orow = bm + ((l >> 4) << 2);
  int ocol = l & 15;
  #pragma unroll
  for (int t = 0; t < NT; t++){
    int c = t*16 + ocol;
    if (c >= F) break;
    #pragma unroll
    for (int jr = 0; jr < 4; jr++){
      int r = orow + jr;
      if (r < N) Y[(size_t)r*F + c] = __float2bfloat16(acc[t][jr]);
    }
  }
}

// ---------------- attention logits per node ----------------
__global__ void k_al(const bf16* __restrict__ xl, const float* __restrict__ asrc, const float* __restrict__ adst,
                     float* __restrict__ als, float* __restrict__ ald, int N, int H, int C){
  int i = blockIdx.x*blockDim.x + threadIdx.x;
  if (i >= N*H) return;
  int h = i % H;
  const bf16* row = xl + (size_t)(i/H)*H*C + (size_t)h*C;
  float s = 0.f, d = 0.f;
  for (int c = 0; c < C; c++){ float v = b2f(row[c]); s += v*asrc[h*C+c]; d += v*adst[h*C+c]; }
  als[i] = s; ald[i] = d;
}

// ---------------- softmax: 2-gather passes, write UNNORMALIZED w once + inv[N,H] ----------------
template<int H>
__global__ void k_coef(const int* __restrict__ rowptr, const int* __restrict__ ssrc,
                       const float* __restrict__ als, const float* __restrict__ ald,
                       float* __restrict__ coef, float* __restrict__ invs, int N){
  int i = blockIdx.x*blockDim.x + threadIdx.x;
  if (i >= N*H) return;
  int node = i / H;
  int h = i - node*H;
  int beg = rowptr[node], end = rowptr[node+1];
  float ad = ald[i];
  float m = -1e30f;
  int p = beg;
  for (; p + 4 <= end; p += 4){
    int s0=ssrc[p], s1=ssrc[p+1], s2=ssrc[p+2], s3=ssrc[p+3];
    float a0 = lrelu(als[s0*H + h] + ad);
    float a1 = lrelu(als[s1*H + h] + ad);
    float a2 = lrelu(als[s2*H + h] + ad);
    float a3 = lrelu(als[s3*H + h] + ad);
    m = fmaxf(m, fmaxf(fmaxf(a0,a1), fmaxf(a2,a3)));
  }
  for (; p < end; p++) m = fmaxf(m, lrelu(als[ssrc[p]*H + h] + ad));
  float s = 0.f;
  p = beg;
  for (; p + 4 <= end; p += 4){
    int s0=ssrc[p], s1=ssrc[p+1], s2=ssrc[p+2], s3=ssrc[p+3];
    float w0 = __expf(lrelu(als[s0*H + h] + ad) - m);
    float w1 = __expf(lrelu(als[s1*H + h] + ad) - m);
    float w2 = __expf(lrelu(als[s2*H + h] + ad) - m);
    float w3 = __expf(lrelu(als[s3*H + h] + ad) - m);
    coef[(size_t)(p+0)*H + h] = w0;
    coef[(size_t)(p+1)*H + h] = w1;
    coef[(size_t)(p+2)*H + h] = w2;
    coef[(size_t)(p+3)*H + h] = w3;
    s += w0 + w1 + w2 + w3;
  }
  for (; p < end; p++){
    float w = __expf(lrelu(als[ssrc[p]*H + h] + ad) - m);
    coef[(size_t)p*H + h] = w;
    s += w;
  }
  invs[i] = 1.f / (s + 1e-16f);
}

// ---------------- GAT aggregation: ushort4-vectorized gather (4 bf16/lane/edge) ----------------
// TPN = F/4 threads per node (node is wave-uniform when TPN <= 64); unroll x4.
template<int H, int C, int NPB>
__global__ void k_gat3(const int* __restrict__ rowptr, const int* __restrict__ ssrc,
                       const bf16* __restrict__ xl, const float* __restrict__ coef,
                       const float* __restrict__ invs, float* __restrict__ out, int N){
  const int F = H*C;
  const int TPN = F/4;
  int tid = threadIdx.x;
  int node = blockIdx.x*NPB + tid/TPN;
  int lt = (tid - (tid/TPN)*TPN)*4;    // starting feature, multiple of 4 (4 | C)
  if (node >= N) return;
  int h = lt / C;
  int beg = rowptr[node], end = rowptr[node+1];
  const float* cof = coef + h;
  const ushort* xlp = reinterpret_cast<const ushort*>(xl) + lt;
  float a0=0.f, a1=0.f, a2=0.f, a3=0.f;
  int p = beg;
  for (; p + 4 <= end; p += 4){
    int s0=ssrc[p], s1=ssrc[p+1], s2=ssrc[p+2], s3=ssrc[p+3];
    float c0 = cof[(size_t)(p+0)*H];
    float c1 = cof[(size_t)(p+1)*H];
    float c2 = cof[(size_t)(p+2)*H];
    float c3 = cof[(size_t)(p+3)*H];
    ushort4 v0 = *reinterpret_cast<const ushort4*>(xlp + (size_t)s0*F);
    ushort4 v1 = *reinterpret_cast<const ushort4*>(xlp + (size_t)s1*F);
    ushort4 v2 = *reinterpret_cast<const ushort4*>(xlp + (size_t)s2*F);
    ushort4 v3 = *reinterpret_cast<const ushort4*>(xlp + (size_t)s3*F);
    a0 += c0*u2f(v0.x); a1 += c0*u2f(v0.y); a2 += c0*u2f(v0.z); a3 += c0*u2f(v0.w);
    a0 += c1*u2f(v1.x); a1 += c1*u2f(v1.y); a2 += c1*u2f(v1.z); a3 += c1*u2f(v1.w);
    a0 += c2*u2f(v2.x); a1 += c2*u2f(v2.y); a2 += c2*u2f(v2.z); a3 += c2*u2f(v2.w);
    a0 += c3*u2f(v3.x); a1 += c3*u2f(v3.y); a2 += c3*u2f(v3.z); a3 += c3*u2f(v3.w);
  }
  for (; p < end; p++){
    int si = ssrc[p];
    float c = cof[(size_t)p*H];
    ushort4 v = *reinterpret_cast<const ushort4*>(xlp + (size_t)si*F);
    a0 += c*u2f(v.x); a1 += c*u2f(v.y); a2 += c*u2f(v.z); a3 += c*u2f(v.w);
  }
  float inv = invs[node*H + h];
  float4 o; o.x = a0*inv; o.y = a1*inv; o.z = a2*inv; o.w = a3*inv;
  *reinterpret_cast<float4*>(out + (size_t)node*F + lt) = o;
}

// ---------------- GAT aggregation, narrow-F path (layer 3) ----------------
template<int H, int C, int NPB>
__global__ void k_gat2(const int* __restrict__ rowptr, const int* __restrict__ ssrc,
                       const bf16* __restrict__ xl, const float* __restrict__ coef,
                       const float* __restrict__ invs, float* __restrict__ out, int N){
  const int F = H*C;
  int tid = threadIdx.x;
  int node = blockIdx.x*NPB + tid/F;
  int lt = tid - (tid/F)*F;
  if (node >= N) return;
  int h = lt / C;
  int beg = rowptr[node], end = rowptr[node+1];
  const float* cof = coef + h;
  const bf16* xlp = xl + lt;
  float acc = 0.f;
  int p = beg;
  for (; p + 8 <= end; p += 8){
    int s0=ssrc[p],   s1=ssrc[p+1], s2=ssrc[p+2], s3=ssrc[p+3];
    int s4=ssrc[p+4], s5=ssrc[p+5], s6=ssrc[p+6], s7=ssrc[p+7];
    float c0 = cof[(size_t)(p+0)*H];
    float c1 = cof[(size_t)(p+1)*H];
    float c2 = cof[(size_t)(p+2)*H];
    float c3 = cof[(size_t)(p+3)*H];
    float c4 = cof[(size_t)(p+4)*H];
    float c5 = cof[(size_t)(p+5)*H];
    float c6 = cof[(size_t)(p+6)*H];
    float c7 = cof[(size_t)(p+7)*H];
    float v0 = b2f(xlp[(size_t)s0*F]);
    float v1 = b2f(xlp[(size_t)s1*F]);
    float v2 = b2f(xlp[(size_t)s2*F]);
    float v3 = b2f(xlp[(size_t)s3*F]);
    float v4 = b2f(xlp[(size_t)s4*F]);
    float v5 = b2f(xlp[(size_t)s5*F]);
    float v6 = b2f(xlp[(size_t)s6*F]);
    float v7 = b2f(xlp[(size_t)s7*F]);
    acc += c0*v0; acc += c1*v1; acc += c2*v2; acc += c3*v3;
    acc += c4*v4; acc += c5*v5; acc += c6*v6; acc += c7*v7;
  }
  for (; p < end; p++){
    int si = ssrc[p];
    acc += cof[(size_t)p*H] * b2f(xlp[(size_t)si*F]);
  }
  out[(size_t)node*F + lt] = acc * invs[node*H + h];
}

// ---------------- BatchNorm ----------------
__global__ void k_bnstats(const float* __restrict__ x, int N, int F, float* __restrict__ sums, float* __restrict__ sumsq){
  int f = threadIdx.x;
  if (f >= F) return;
  int r0 = blockIdx.x*128;
  int r1 = min(r0+128, N);
  float s=0.f, s2=0.f;
  for (int r=r0; r<r1; r++){ float v = x[(size_t)r*F + f]; s += v; s2 += v*v; }
  atomicAdd(&sums[f], s);
  atomicAdd(&sumsq[f], s2);
}

// BN + ELU, output bf16 (feeds the next MFMA GEMM directly)
__global__ void k_bnapply_elu(const float* __restrict__ x, const float* __restrict__ sums, const float* __restrict__ sumsq,
                              const float* __restrict__ g, const float* __restrict__ beta,
                              bf16* __restrict__ y, int N, int F){
  int i = blockIdx.x*blockDim.x + threadIdx.x;
  if (i >= N*F) return;
  int f = i % F;
  float mu = sums[f] / (float)N;
  float var = sumsq[f] / (float)N - mu*mu;
  float inv = rsqrtf(var + 1e-5f);
  float v = (x[i]-mu)*inv*g[f] + beta[f];
  v = v > 0.f ? v : (__expf(v) - 1.f);
  y[i] = __float2bfloat16(v);
}

// ---------------- final: +bias, log_softmax over 10 classes ----------------
__global__ void k_final(const float* __restrict__ x, const float* __restrict__ b3, float* __restrict__ out, int N){
  int n = blockIdx.x*blockDim.x + threadIdx.x;
  if (n >= N) return;
  float v[10];
  float m = -1e30f;
  #pragma unroll
  for (int c=0;c<10;c++){ v[c] = x[n*10+c] + b3[c]; m = fmaxf(m, v[c]); }
  float s = 0.f;
  #pragma unroll
  for (int c=0;c<10;c++) s += __expf(v[c]-m);
  float ls = logf(s);
  #pragma unroll
  for (int c=0;c<10;c++) out[n*10+c] = v[c] - m - ls;
}

extern "C" void kernel_launch(void* const* d_in, const int* in_sizes, int n_in,
                              void* d_out, int out_size, void* d_ws, size_t ws_size,
                              hipStream_t stream){
  const float* x   = (const float*)d_in[0];
  const int*  ei   = (const int*)d_in[1];
  const float* W1  = (const float*)d_in[2];
  const float* as1 = (const float*)d_in[3];
  const float* ad1 = (const float*)d_in[4];
  // d_in[5] = b1: cancels under BatchNorm (mean subtraction) -> skipped
  const float* g1  = (const float*)d_in[6];
  const float* be1 = (const float*)d_in[7];
  const float* W2  = (const float*)d_in[8];
  const float* as2 = (const float*)d_in[9];
  const float* ad2 = (const float*)d_in[10];
  // d_in[11] = b2: cancels under BatchNorm -> skipped
  const float* g2  = (const float*)d_in[12];
  const float* be2 = (const float*)d_in[13];
  const float* W3  = (const float*)d_in[14];
  const float* as3 = (const float*)d_in[15];
  const float* ad3 = (const float*)d_in[16];
  const float* b3  = (const float*)d_in[17];
  float* out = (float*)d_out;
  (void)n_in; (void)out_size; (void)ws_size;

  int N = in_sizes[0] / 128;     // 50000
  int E = in_sizes[1] / 2;       // 850000
  const int* src = ei;
  const int* dst = ei + E;

  char* w = (char*)d_ws;
  size_t off = 0;
  auto alloc = [&](size_t bytes) -> void* {
    void* p = w + off;
    off += (bytes + 255) & ~(size_t)255;
    return p;
  };
  bf16* xlb    = (bf16*)alloc((size_t)N*256*2);    // GEMM out (bf16), per layer
  float* gout  = (float*)alloc((size_t)N*256*4);   // GAT out (fp32)
  bf16*  hb    = (bf16*)alloc((size_t)N*256*2);    // BN+ELU out (bf16) = next GEMM input
  float* coef  = (float*)alloc((size_t)E*8*4);     // softmax weights (unnormalized), CSR-ordered
  bf16*  xb    = (bf16*)alloc((size_t)N*128*2);    // x cast to bf16
  bf16*  Wt1   = (bf16*)alloc((size_t)128*128*2);  // W^T bf16
  bf16*  Wt2   = (bf16*)alloc((size_t)256*128*2);
  bf16*  Wt3   = (bf16*)alloc((size_t)16*256*2);   // padded to 16 cols
  float* als   = (float*)alloc((size_t)N*8*4);
  float* ald   = (float*)alloc((size_t)N*8*4);
  float* invs  = (float*)alloc((size_t)N*8*4);
  int* rowptr  = (int*)alloc((size_t)(N+1)*4);
  int* counts  = (int*)alloc((size_t)N*4);
  int* cursor  = (int*)alloc((size_t)N*4);
  int* ssrc    = (int*)alloc((size_t)E*4);
  int* bsums   = (int*)alloc(256*4);
  float* sums  = (float*)alloc(256*4);
  float* sumsq = (float*)alloc(256*4);

  // ---- CSR by dst (reused for all 3 layers) ----
  hipMemsetAsync(counts, 0, (size_t)N*4, stream);
  hipMemsetAsync(cursor, 0, (size_t)N*4, stream);
  k_hist<<<(E+255)/256, 256, 0, stream>>>(dst, E, counts);
  int nchunks = (N + 1023)/1024;
  k_scan_block<<<nchunks, 1024, 0, stream>>>(counts, N, rowptr, bsums);
  k_scan_sums<<<1, 64, 0, stream>>>(bsums, nchunks);
  k_scan_add<<<(N+1+255)/256, 256, 0, stream>>>(rowptr, bsums, N, E);
  k_scatter<<<(E+255)/256, 256, 0, stream>>>(src, dst, E, rowptr, cursor, ssrc);

  // ---- dtype prep ----
  k_cast<<<((N*128/4)+255)/256, 256, 0, stream>>>(x, xb, N*128/4);
  k_wtrans<<<(128*128+255)/256, 256, 0, stream>>>(W1, Wt1, 128, 128);
  k_wtrans<<<(128*256+255)/256, 256, 0, stream>>>(W2, Wt2, 128, 256);
  hipMemsetAsync(Wt3, 0, (size_t)16*256*2, stream);
  k_wtrans<<<(256*10+255)/256, 256, 0, stream>>>(W3, Wt3, 256, 10);

  int gblk = (N + 63)/64;

  // ---- layer 1: x[N,128] -> h1[N,128] ----
  {
    const int F=128, H=8;
    k_gemm_mfma<128,128,128><<<gblk, 256, 0, stream>>>(xb, Wt1, xlb, N);
    k_al<<<(N*H+255)/256, 256, 0, stream>>>(xlb, as1, ad1, als, ald, N, H, 16);
    k_coef<8><<<(N*H+255)/256, 256, 0, stream>>>(rowptr, ssrc, als, ald, coef, invs, N);
    k_gat3<8,16,8><<<(N+7)/8, 256, 0, stream>>>(rowptr, ssrc, xlb, coef, invs, gout, N);
    hipMemsetAsync(sums, 0, 256*4, stream);
    hipMemsetAsync(sumsq, 0, 256*4, stream);
    k_bnstats<<<(N+127)/128, F, 0, stream>>>(gout, N, F, sums, sumsq);
    k_bnapply_elu<<<(int)(((size_t)N*F+255)/256), 256, 0, stream>>>(gout, sums, sumsq, g1, be1, hb, N, F);
  }
  // ---- layer 2: h1[N,128] -> h2[N,256] ----
  {
    const int F=256, H=8;
    k_gemm_mfma<128,256,256><<<gblk, 256, 0, stream>>>(hb, Wt2, xlb, N);
    k_al<<<(N*H+255)/256, 256, 0, stream>>>(xlb, as2, ad2, als, ald, N, H, 32);
    k_coef<8><<<(N*H+255)/256, 256, 0, stream>>>(rowptr, ssrc, als, ald, coef, invs, N);
    k_gat3<8,32,4><<<(N+3)/4, 256, 0, stream>>>(rowptr, ssrc, xlb, coef, invs, gout, N);
    hipMemsetAsync(sums, 0, 256*4, stream);
    hipMemsetAsync(sumsq, 0, 256*4, stream);
    k_bnstats<<<(N+127)/128, F, 0, stream>>>(gout, N, F, sums, sumsq);
    k_bnapply_elu<<<(int)(((size_t)N*F+255)/256), 256, 0, stream>>>(gout, sums, sumsq, g2, be2, hb, N, F);
  }
  // ---- layer 3: h2[N,256] -> logits[N,10] ----
  {
    const int H=1;
    k_gemm_mfma<256,10,16><<<gblk, 256, 0, stream>>>(hb, Wt3, xlb, N);
    k_al<<<(N*H+255)/256, 256, 0, stream>>>(xlb, as3, ad3, als, ald, N, H, 10);
    k_coef<1><<<(N+255)/256, 256, 0, stream>>>(rowptr, ssrc, als, ald, coef, invs, N);
    k_gat2<1,10,32><<<(N+31)/32, 320, 0, stream>>>(rowptr, ssrc, xlb, coef, invs, gout, N);
    k_final<<<(N+255)/256, 256, 0, stream>>>(gout, b3, out, N);
  }
}

// Round 15
// 644.289 us; speedup vs baseline: 2.0472x; 1.0030x over previous
//
#include <hip/hip_runtime.h>
#include <hip/hip_bf16.h>
#include <cstdint>
#include <cstddef>

using bf16 = __hip_bfloat16;
typedef __attribute__((ext_vector_type(8))) short short8;
typedef __attribute__((ext_vector_type(4))) float f32x4;

static __device__ __forceinline__ float lrelu(float x){ return x > 0.f ? x : 0.2f*x; }
static __device__ __forceinline__ float b2f(bf16 v){ return __bfloat162float(v); }
static __device__ __forceinline__ float u2f(unsigned short u){ return __uint_as_float(((unsigned)u) << 16); }

// ---------------- CSR build ----------------
__global__ void k_hist(const int* __restrict__ dst, int E, int* __restrict__ counts){
  int i = blockIdx.x*blockDim.x + threadIdx.x;
  if (i < E) atomicAdd(&counts[dst[i]], 1);
}

__global__ void k_scan_block(const int* __restrict__ counts, int n, int* __restrict__ rowptr, int* __restrict__ bsums){
  __shared__ int buf[1024];
  int tid = threadIdx.x;
  int i = blockIdx.x*1024 + tid;
  int v = (i < n) ? counts[i] : 0;
  buf[tid] = v;
  __syncthreads();
  for (int off = 1; off < 1024; off <<= 1){
    int t = (tid >= off) ? buf[tid-off] : 0;
    __syncthreads();
    buf[tid] += t;
    __syncthreads();
  }
  if (i < n) rowptr[i] = buf[tid] - v;   // local exclusive
  if (tid == 1023) bsums[blockIdx.x] = buf[1023];
}

__global__ void k_scan_sums(int* bsums, int nb){
  if (threadIdx.x == 0 && blockIdx.x == 0){
    int run = 0;
    for (int i = 0; i < nb; i++){ int t = bsums[i]; bsums[i] = run; run += t; }
  }
}

__global__ void k_scan_add(int* __restrict__ rowptr, const int* __restrict__ bsums, int n, int E){
  int i = blockIdx.x*blockDim.x + threadIdx.x;
  if (i < n) rowptr[i] += bsums[i >> 10];
  if (i == n) rowptr[n] = E;
}

__global__ void k_scatter(const int* __restrict__ src, const int* __restrict__ dst, int E,
                          const int* __restrict__ rowptr, int* __restrict__ cursor, int* __restrict__ ssrc){
  int i = blockIdx.x*blockDim.x + threadIdx.x;
  if (i < E){
    int d = dst[i];
    int p = atomicAdd(&cursor[d], 1);
    ssrc[rowptr[d] + p] = src[i];
  }
}

// ---------------- dtype prep ----------------
__global__ void k_cast(const float* __restrict__ in, bf16* __restrict__ outp, int n4){
  int i = blockIdx.x*blockDim.x + threadIdx.x;
  if (i >= n4) return;
  float4 v = reinterpret_cast<const float4*>(in)[i];
  bf16* o = outp + (size_t)i*4;
  o[0] = __float2bfloat16(v.x); o[1] = __float2bfloat16(v.y);
  o[2] = __float2bfloat16(v.z); o[3] = __float2bfloat16(v.w);
}

// Wt[f*K + k] = bf16(W[k*F + f])
__global__ void k_wtrans(const float* __restrict__ W, bf16* __restrict__ Wt, int K, int F){
  int i = blockIdx.x*blockDim.x + threadIdx.x;
  if (i >= K*F) return;
  int k = i / F, f = i - k*F;
  Wt[(size_t)f*K + k] = __float2bfloat16(W[i]);
}

// ---------------- MFMA bf16 GEMM: Y[N,F](bf16) = A[N,K](bf16) @ Wt[FPAD,K]^T ----------------
template<int K, int F, int FPAD>
__global__ __launch_bounds__(256) void k_gemm_mfma(const bf16* __restrict__ A, const bf16* __restrict__ Wt,
                                                   bf16* __restrict__ Y, int N){
  const int NT = FPAD/16;
  int w = threadIdx.x >> 6;       // wave 0..3
  int l = threadIdx.x & 63;       // lane
  int bm = blockIdx.x*64 + w*16;
  int arow = bm + (l & 15);
  int arowc = min(arow, N-1);
  int koff = 8*(l >> 4);
  f32x4 acc[NT];
  #pragma unroll
  for (int t = 0; t < NT; t++) acc[t] = f32x4{0.f,0.f,0.f,0.f};
  const bf16* ap = A + (size_t)arowc*K + koff;
  const bf16* bp = Wt + (size_t)(l & 15)*K + koff;
  for (int k0 = 0; k0 < K; k0 += 32){
    short8 a = *reinterpret_cast<const short8*>(ap + k0);
    #pragma unroll
    for (int t = 0; t < NT; t++){
      short8 b = *reinterpret_cast<const short8*>(bp + (size_t)t*16*K + k0);
      acc[t] = __builtin_amdgcn_mfma_f32_16x16x32_bf16(a, b, acc[t], 0, 0, 0);
    }
  }
  int orow = bm + ((l >> 4) << 2);
  int ocol = l & 15;
  #pragma unroll
  for (int t = 0; t < NT; t++){
    int c = t*16 + ocol;
    if (c >= F) break;
    #pragma unroll
    for (int jr = 0; jr < 4; jr++){
      int r = orow + jr;
      if (r < N) Y[(size_t)r*F + c] = __float2bfloat16(acc[t][jr]);
    }
  }
}

// ---------------- attention logits per node ----------------
__global__ void k_al(const bf16* __restrict__ xl, const float* __restrict__ asrc, const float* __restrict__ adst,
                     float* __restrict__ als, float* __restrict__ ald, int N, int H, int C){
  int i = blockIdx.x*blockDim.x + threadIdx.x;
  if (i >= N*H) return;
  int h = i % H;
  const bf16* row = xl + (size_t)(i/H)*H*C + (size_t)h*C;
  float s = 0.f, d = 0.f;
  for (int c = 0; c < C; c++){ float v = b2f(row[c]); s += v*asrc[h*C+c]; d += v*adst[h*C+c]; }
  als[i] = s; ald[i] = d;
}

// ---------------- softmax: 2-gather passes, write UNNORMALIZED w once + inv[N,H] ----------------
template<int H>
__global__ void k_coef(const int* __restrict__ rowptr, const int* __restrict__ ssrc,
                       const float* __restrict__ als, const float* __restrict__ ald,
                       float* __restrict__ coef, float* __restrict__ invs, int N){
  int i = blockIdx.x*blockDim.x + threadIdx.x;
  if (i >= N*H) return;
  int node = i / H;
  int h = i - node*H;
  int beg = rowptr[node], end = rowptr[node+1];
  float ad = ald[i];
  float m = -1e30f;
  int p = beg;
  for (; p + 4 <= end; p += 4){
    int s0=ssrc[p], s1=ssrc[p+1], s2=ssrc[p+2], s3=ssrc[p+3];
    float a0 = lrelu(als[s0*H + h] + ad);
    float a1 = lrelu(als[s1*H + h] + ad);
    float a2 = lrelu(als[s2*H + h] + ad);
    float a3 = lrelu(als[s3*H + h] + ad);
    m = fmaxf(m, fmaxf(fmaxf(a0,a1), fmaxf(a2,a3)));
  }
  for (; p < end; p++) m = fmaxf(m, lrelu(als[ssrc[p]*H + h] + ad));
  float s = 0.f;
  p = beg;
  for (; p + 4 <= end; p += 4){
    int s0=ssrc[p], s1=ssrc[p+1], s2=ssrc[p+2], s3=ssrc[p+3];
    float w0 = __expf(lrelu(als[s0*H + h] + ad) - m);
    float w1 = __expf(lrelu(als[s1*H + h] + ad) - m);
    float w2 = __expf(lrelu(als[s2*H + h] + ad) - m);
    float w3 = __expf(lrelu(als[s3*H + h] + ad) - m);
    coef[(size_t)(p+0)*H + h] = w0;
    coef[(size_t)(p+1)*H + h] = w1;
    coef[(size_t)(p+2)*H + h] = w2;
    coef[(size_t)(p+3)*H + h] = w3;
    s += w0 + w1 + w2 + w3;
  }
  for (; p < end; p++){
    float w = __expf(lrelu(als[ssrc[p]*H + h] + ad) - m);
    coef[(size_t)p*H + h] = w;
    s += w;
  }
  invs[i] = 1.f / (s + 1e-16f);
}

// ---------------- GAT aggregation: ushort4 gather, unroll x8, bf16 output ----------------
// TPN = F/4 threads per node; unroll x8 for MLP.
template<int H, int C, int NPB>
__global__ void k_gat3(const int* __restrict__ rowptr, const int* __restrict__ ssrc,
                       const bf16* __restrict__ xl, const float* __restrict__ coef,
                       const float* __restrict__ invs, bf16* __restrict__ out, int N){
  const int F = H*C;
  const int TPN = F/4;
  int tid = threadIdx.x;
  int node = blockIdx.x*NPB + tid/TPN;
  int lt = (tid - (tid/TPN)*TPN)*4;    // starting feature, multiple of 4 (4 | C)
  if (node >= N) return;
  int h = lt / C;
  int beg = rowptr[node], end = rowptr[node+1];
  const float* cof = coef + h;
  const ushort* xlp = reinterpret_cast<const ushort*>(xl) + lt;
  float a0=0.f, a1=0.f, a2=0.f, a3=0.f;
  int p = beg;
  for (; p + 8 <= end; p += 8){
    int s0=ssrc[p],   s1=ssrc[p+1], s2=ssrc[p+2], s3=ssrc[p+3];
    int s4=ssrc[p+4], s5=ssrc[p+5], s6=ssrc[p+6], s7=ssrc[p+7];
    float c0 = cof[(size_t)(p+0)*H];
    float c1 = cof[(size_t)(p+1)*H];
    float c2 = cof[(size_t)(p+2)*H];
    float c3 = cof[(size_t)(p+3)*H];
    float c4 = cof[(size_t)(p+4)*H];
    float c5 = cof[(size_t)(p+5)*H];
    float c6 = cof[(size_t)(p+6)*H];
    float c7 = cof[(size_t)(p+7)*H];
    ushort4 v0 = *reinterpret_cast<const ushort4*>(xlp + (size_t)s0*F);
    ushort4 v1 = *reinterpret_cast<const ushort4*>(xlp + (size_t)s1*F);
    ushort4 v2 = *reinterpret_cast<const ushort4*>(xlp + (size_t)s2*F);
    ushort4 v3 = *reinterpret_cast<const ushort4*>(xlp + (size_t)s3*F);
    ushort4 v4 = *reinterpret_cast<const ushort4*>(xlp + (size_t)s4*F);
    ushort4 v5 = *reinterpret_cast<const ushort4*>(xlp + (size_t)s5*F);
    ushort4 v6 = *reinterpret_cast<const ushort4*>(xlp + (size_t)s6*F);
    ushort4 v7 = *reinterpret_cast<const ushort4*>(xlp + (size_t)s7*F);
    a0 += c0*u2f(v0.x); a1 += c0*u2f(v0.y); a2 += c0*u2f(v0.z); a3 += c0*u2f(v0.w);
    a0 += c1*u2f(v1.x); a1 += c1*u2f(v1.y); a2 += c1*u2f(v1.z); a3 += c1*u2f(v1.w);
    a0 += c2*u2f(v2.x); a1 += c2*u2f(v2.y); a2 += c2*u2f(v2.z); a3 += c2*u2f(v2.w);
    a0 += c3*u2f(v3.x); a1 += c3*u2f(v3.y); a2 += c3*u2f(v3.z); a3 += c3*u2f(v3.w);
    a0 += c4*u2f(v4.x); a1 += c4*u2f(v4.y); a2 += c4*u2f(v4.z); a3 += c4*u2f(v4.w);
    a0 += c5*u2f(v5.x); a1 += c5*u2f(v5.y); a2 += c5*u2f(v5.z); a3 += c5*u2f(v5.w);
    a0 += c6*u2f(v6.x); a1 += c6*u2f(v6.y); a2 += c6*u2f(v6.z); a3 += c6*u2f(v6.w);
    a0 += c7*u2f(v7.x); a1 += c7*u2f(v7.y); a2 += c7*u2f(v7.z); a3 += c7*u2f(v7.w);
  }
  for (; p + 4 <= end; p += 4){
    int s0=ssrc[p], s1=ssrc[p+1], s2=ssrc[p+2], s3=ssrc[p+3];
    float c0 = cof[(size_t)(p+0)*H];
    float c1 = cof[(size_t)(p+1)*H];
    float c2 = cof[(size_t)(p+2)*H];
    float c3 = cof[(size_t)(p+3)*H];
    ushort4 v0 = *reinterpret_cast<const ushort4*>(xlp + (size_t)s0*F);
    ushort4 v1 = *reinterpret_cast<const ushort4*>(xlp + (size_t)s1*F);
    ushort4 v2 = *reinterpret_cast<const ushort4*>(xlp + (size_t)s2*F);
    ushort4 v3 = *reinterpret_cast<const ushort4*>(xlp + (size_t)s3*F);
    a0 += c0*u2f(v0.x); a1 += c0*u2f(v0.y); a2 += c0*u2f(v0.z); a3 += c0*u2f(v0.w);
    a0 += c1*u2f(v1.x); a1 += c1*u2f(v1.y); a2 += c1*u2f(v1.z); a3 += c1*u2f(v1.w);
    a0 += c2*u2f(v2.x); a1 += c2*u2f(v2.y); a2 += c2*u2f(v2.z); a3 += c2*u2f(v2.w);
    a0 += c3*u2f(v3.x); a1 += c3*u2f(v3.y); a2 += c3*u2f(v3.z); a3 += c3*u2f(v3.w);
  }
  for (; p < end; p++){
    int si = ssrc[p];
    float c = cof[(size_t)p*H];
    ushort4 v = *reinterpret_cast<const ushort4*>(xlp + (size_t)si*F);
    a0 += c*u2f(v.x); a1 += c*u2f(v.y); a2 += c*u2f(v.z); a3 += c*u2f(v.w);
  }
  float inv = invs[node*H + h];
  bf16 ov[4];
  ov[0] = __float2bfloat16(a0*inv);
  ov[1] = __float2bfloat16(a1*inv);
  ov[2] = __float2bfloat16(a2*inv);
  ov[3] = __float2bfloat16(a3*inv);
  *reinterpret_cast<ushort4*>(reinterpret_cast<ushort*>(out) + (size_t)node*F + lt) =
      *reinterpret_cast<ushort4*>(ov);
}

// ---------------- GAT aggregation, narrow-F path (layer 3, fp32 out) ----------------
template<int H, int C, int NPB>
__global__ void k_gat2(const int* __restrict__ rowptr, const int* __restrict__ ssrc,
                       const bf16* __restrict__ xl, const float* __restrict__ coef,
                       const float* __restrict__ invs, float* __restrict__ out, int N){
  const int F = H*C;
  int tid = threadIdx.x;
  int node = blockIdx.x*NPB + tid/F;
  int lt = tid - (tid/F)*F;
  if (node >= N) return;
  int h = lt / C;
  int beg = rowptr[node], end = rowptr[node+1];
  const float* cof = coef + h;
  const bf16* xlp = xl + lt;
  float acc = 0.f;
  int p = beg;
  for (; p + 8 <= end; p += 8){
    int s0=ssrc[p],   s1=ssrc[p+1], s2=ssrc[p+2], s3=ssrc[p+3];
    int s4=ssrc[p+4], s5=ssrc[p+5], s6=ssrc[p+6], s7=ssrc[p+7];
    float c0 = cof[(size_t)(p+0)*H];
    float c1 = cof[(size_t)(p+1)*H];
    float c2 = cof[(size_t)(p+2)*H];
    float c3 = cof[(size_t)(p+3)*H];
    float c4 = cof[(size_t)(p+4)*H];
    float c5 = cof[(size_t)(p+5)*H];
    float c6 = cof[(size_t)(p+6)*H];
    float c7 = cof[(size_t)(p+7)*H];
    float v0 = b2f(xlp[(size_t)s0*F]);
    float v1 = b2f(xlp[(size_t)s1*F]);
    float v2 = b2f(xlp[(size_t)s2*F]);
    float v3 = b2f(xlp[(size_t)s3*F]);
    float v4 = b2f(xlp[(size_t)s4*F]);
    float v5 = b2f(xlp[(size_t)s5*F]);
    float v6 = b2f(xlp[(size_t)s6*F]);
    float v7 = b2f(xlp[(size_t)s7*F]);
    acc += c0*v0; acc += c1*v1; acc += c2*v2; acc += c3*v3;
    acc += c4*v4; acc += c5*v5; acc += c6*v6; acc += c7*v7;
  }
  for (; p < end; p++){
    int si = ssrc[p];
    acc += cof[(size_t)p*H] * b2f(xlp[(size_t)si*F]);
  }
  out[(size_t)node*F + lt] = acc * invs[node*H + h];
}

// ---------------- BatchNorm (bf16 input) ----------------
__global__ void k_bnstats(const bf16* __restrict__ x, int N, int F, float* __restrict__ sums, float* __restrict__ sumsq){
  int f = threadIdx.x;
  if (f >= F) return;
  int r0 = blockIdx.x*128;
  int r1 = min(r0+128, N);
  float s=0.f, s2=0.f;
  for (int r=r0; r<r1; r++){ float v = b2f(x[(size_t)r*F + f]); s += v; s2 += v*v; }
  atomicAdd(&sums[f], s);
  atomicAdd(&sumsq[f], s2);
}

// BN + ELU: bf16 in, bf16 out (feeds the next MFMA GEMM directly)
__global__ void k_bnapply_elu(const bf16* __restrict__ x, const float* __restrict__ sums, const float* __restrict__ sumsq,
                              const float* __restrict__ g, const float* __restrict__ beta,
                              bf16* __restrict__ y, int N, int F){
  int i = blockIdx.x*blockDim.x + threadIdx.x;
  if (i >= N*F) return;
  int f = i % F;
  float mu = sums[f] / (float)N;
  float var = sumsq[f] / (float)N - mu*mu;
  float inv = rsqrtf(var + 1e-5f);
  float v = (b2f(x[i])-mu)*inv*g[f] + beta[f];
  v = v > 0.f ? v : (__expf(v) - 1.f);
  y[i] = __float2bfloat16(v);
}

// ---------------- final: +bias, log_softmax over 10 classes ----------------
__global__ void k_final(const float* __restrict__ x, const float* __restrict__ b3, float* __restrict__ out, int N){
  int n = blockIdx.x*blockDim.x + threadIdx.x;
  if (n >= N) return;
  float v[10];
  float m = -1e30f;
  #pragma unroll
  for (int c=0;c<10;c++){ v[c] = x[n*10+c] + b3[c]; m = fmaxf(m, v[c]); }
  float s = 0.f;
  #pragma unroll
  for (int c=0;c<10;c++) s += __expf(v[c]-m);
  float ls = logf(s);
  #pragma unroll
  for (int c=0;c<10;c++) out[n*10+c] = v[c] - m - ls;
}

extern "C" void kernel_launch(void* const* d_in, const int* in_sizes, int n_in,
                              void* d_out, int out_size, void* d_ws, size_t ws_size,
                              hipStream_t stream){
  const float* x   = (const float*)d_in[0];
  const int*  ei   = (const int*)d_in[1];
  const float* W1  = (const float*)d_in[2];
  const float* as1 = (const float*)d_in[3];
  const float* ad1 = (const float*)d_in[4];
  // d_in[5] = b1: cancels under BatchNorm (mean subtraction) -> skipped
  const float* g1  = (const float*)d_in[6];
  const float* be1 = (const float*)d_in[7];
  const float* W2  = (const float*)d_in[8];
  const float* as2 = (const float*)d_in[9];
  const float* ad2 = (const float*)d_in[10];
  // d_in[11] = b2: cancels under BatchNorm -> skipped
  const float* g2  = (const float*)d_in[12];
  const float* be2 = (const float*)d_in[13];
  const float* W3  = (const float*)d_in[14];
  const float* as3 = (const float*)d_in[15];
  const float* ad3 = (const float*)d_in[16];
  const float* b3  = (const float*)d_in[17];
  float* out = (float*)d_out;
  (void)n_in; (void)out_size; (void)ws_size;

  int N = in_sizes[0] / 128;     // 50000
  int E = in_sizes[1] / 2;       // 850000
  const int* src = ei;
  const int* dst = ei + E;

  char* w = (char*)d_ws;
  size_t off = 0;
  auto alloc = [&](size_t bytes) -> void* {
    void* p = w + off;
    off += (bytes + 255) & ~(size_t)255;
    return p;
  };
  bf16* xlb    = (bf16*)alloc((size_t)N*256*2);    // GEMM out (bf16), per layer
  bf16*  goutb = (bf16*)alloc((size_t)N*256*2);    // GAT out (bf16, layers 1-2)
  float* goutf = (float*)alloc((size_t)N*16*4);    // GAT out (fp32, layer 3)
  bf16*  hb    = (bf16*)alloc((size_t)N*256*2);    // BN+ELU out (bf16) = next GEMM input
  float* coef  = (float*)alloc((size_t)E*8*4);     // softmax weights (unnormalized), CSR-ordered
  bf16*  xb    = (bf16*)alloc((size_t)N*128*2);    // x cast to bf16
  bf16*  Wt1   = (bf16*)alloc((size_t)128*128*2);  // W^T bf16
  bf16*  Wt2   = (bf16*)alloc((size_t)256*128*2);
  bf16*  Wt3   = (bf16*)alloc((size_t)16*256*2);   // padded to 16 cols
  float* als   = (float*)alloc((size_t)N*8*4);
  float* ald   = (float*)alloc((size_t)N*8*4);
  float* invs  = (float*)alloc((size_t)N*8*4);
  int* rowptr  = (int*)alloc((size_t)(N+1)*4);
  int* counts  = (int*)alloc((size_t)N*4);
  int* cursor  = (int*)alloc((size_t)N*4);
  int* ssrc    = (int*)alloc((size_t)E*4);
  int* bsums   = (int*)alloc(256*4);
  float* sums  = (float*)alloc(256*4);
  float* sumsq = (float*)alloc(256*4);

  // ---- CSR by dst (reused for all 3 layers) ----
  hipMemsetAsync(counts, 0, (size_t)N*4, stream);
  hipMemsetAsync(cursor, 0, (size_t)N*4, stream);
  k_hist<<<(E+255)/256, 256, 0, stream>>>(dst, E, counts);
  int nchunks = (N + 1023)/1024;
  k_scan_block<<<nchunks, 1024, 0, stream>>>(counts, N, rowptr, bsums);
  k_scan_sums<<<1, 64, 0, stream>>>(bsums, nchunks);
  k_scan_add<<<(N+1+255)/256, 256, 0, stream>>>(rowptr, bsums, N, E);
  k_scatter<<<(E+255)/256, 256, 0, stream>>>(src, dst, E, rowptr, cursor, ssrc);

  // ---- dtype prep ----
  k_cast<<<((N*128/4)+255)/256, 256, 0, stream>>>(x, xb, N*128/4);
  k_wtrans<<<(128*128+255)/256, 256, 0, stream>>>(W1, Wt1, 128, 128);
  k_wtrans<<<(128*256+255)/256, 256, 0, stream>>>(W2, Wt2, 128, 256);
  hipMemsetAsync(Wt3, 0, (size_t)16*256*2, stream);
  k_wtrans<<<(256*10+255)/256, 256, 0, stream>>>(W3, Wt3, 256, 10);

  int gblk = (N + 63)/64;

  // ---- layer 1: x[N,128] -> h1[N,128] ----
  {
    const int F=128, H=8;
    k_gemm_mfma<128,128,128><<<gblk, 256, 0, stream>>>(xb, Wt1, xlb, N);
    k_al<<<(N*H+255)/256, 256, 0, stream>>>(xlb, as1, ad1, als, ald, N, H, 16);
    k_coef<8><<<(N*H+255)/256, 256, 0, stream>>>(rowptr, ssrc, als, ald, coef, invs, N);
    k_gat3<8,16,8><<<(N+7)/8, 256, 0, stream>>>(rowptr, ssrc, xlb, coef, invs, goutb, N);
    hipMemsetAsync(sums, 0, 256*4, stream);
    hipMemsetAsync(sumsq, 0, 256*4, stream);
    k_bnstats<<<(N+127)/128, F, 0, stream>>>(goutb, N, F, sums, sumsq);
    k_bnapply_elu<<<(int)(((size_t)N*F+255)/256), 256, 0, stream>>>(goutb, sums, sumsq, g1, be1, hb, N, F);
  }
  // ---- layer 2: h1[N,128] -> h2[N,256] ----
  {
    const int F=256, H=8;
    k_gemm_mfma<128,256,256><<<gblk, 256, 0, stream>>>(hb, Wt2, xlb, N);
    k_al<<<(N*H+255)/256, 256, 0, stream>>>(xlb, as2, ad2, als, ald, N, H, 32);
    k_coef<8><<<(N*H+255)/256, 256, 0, stream>>>(rowptr, ssrc, als, ald, coef, invs, N);
    k_gat3<8,32,4><<<(N+3)/4, 256, 0, stream>>>(rowptr, ssrc, xlb, coef, invs, goutb, N);
    hipMemsetAsync(sums, 0, 256*4, stream);
    hipMemsetAsync(sumsq, 0, 256*4, stream);
    k_bnstats<<<(N+127)/128, F, 0, stream>>>(goutb, N, F, sums, sumsq);
    k_bnapply_elu<<<(int)(((size_t)N*F+255)/256), 256, 0, stream>>>(goutb, sums, sumsq, g2, be2, hb, N, F);
  }
  // ---- layer 3: h2[N,256] -> logits[N,10] ----
  {
    const int H=1;
    k_gemm_mfma<256,10,16><<<gblk, 256, 0, stream>>>(hb, Wt3, xlb, N);
    k_al<<<(N*H+255)/256, 256, 0, stream>>>(xlb, as3, ad3, als, ald, N, H, 10);
    k_coef<1><<<(N+255)/256, 256, 0, stream>>>(rowptr, ssrc, als, ald, coef, invs, N);
    k_gat2<1,10,32><<<(N+31)/32, 320, 0, stream>>>(rowptr, ssrc, xlb, coef, invs, goutf, N);
    k_final<<<(N+255)/256, 256, 0, stream>>>(goutf, b3, out, N);
  }
}

// Round 17
// 579.842 us; speedup vs baseline: 2.2748x; 1.1111x over previous
//
#include <hip/hip_runtime.h>
#include <hip/hip_bf16.h>
#include <cstdint>
#include <cstddef>

using bf16 = __hip_bfloat16;
typedef __attribute__((ext_vector_type(8))) short short8;
typedef __attribute__((ext_vector_type(4))) float f32x4;

static __device__ __forceinline__ float lrelu(float x){ return x > 0.f ? x : 0.2f*x; }
static __device__ __forceinline__ float b2f(bf16 v){ return __bfloat162float(v); }
static __device__ __forceinline__ float u2f(unsigned short u){ return __uint_as_float(((unsigned)u) << 16); }

// ---------------- CSR build ----------------
__global__ void k_hist(const int* __restrict__ dst, int E, int* __restrict__ counts){
  int i = blockIdx.x*blockDim.x + threadIdx.x;
  if (i < E) atomicAdd(&counts[dst[i]], 1);
}

__global__ void k_scan_block(const int* __restrict__ counts, int n, int* __restrict__ rowptr, int* __restrict__ bsums){
  __shared__ int buf[1024];
  int tid = threadIdx.x;
  int i = blockIdx.x*1024 + tid;
  int v = (i < n) ? counts[i] : 0;
  buf[tid] = v;
  __syncthreads();
  for (int off = 1; off < 1024; off <<= 1){
    int t = (tid >= off) ? buf[tid-off] : 0;
    __syncthreads();
    buf[tid] += t;
    __syncthreads();
  }
  if (i < n) rowptr[i] = buf[tid] - v;   // local exclusive
  if (tid == 1023) bsums[blockIdx.x] = buf[1023];
}

__global__ void k_scan_sums(int* bsums, int nb){
  if (threadIdx.x == 0 && blockIdx.x == 0){
    int run = 0;
    for (int i = 0; i < nb; i++){ int t = bsums[i]; bsums[i] = run; run += t; }
  }
}

__global__ void k_scan_add(int* __restrict__ rowptr, const int* __restrict__ bsums, int n, int E){
  int i = blockIdx.x*blockDim.x + threadIdx.x;
  if (i < n) rowptr[i] += bsums[i >> 10];
  if (i == n) rowptr[n] = E;
}

__global__ void k_scatter(const int* __restrict__ src, const int* __restrict__ dst, int E,
                          const int* __restrict__ rowptr, int* __restrict__ cursor, int* __restrict__ ssrc){
  int i = blockIdx.x*blockDim.x + threadIdx.x;
  if (i < E){
    int d = dst[i];
    int p = atomicAdd(&cursor[d], 1);
    ssrc[rowptr[d] + p] = src[i];
  }
}

// ---------------- dtype prep ----------------
__global__ void k_cast(const float* __restrict__ in, bf16* __restrict__ outp, int n4){
  int i = blockIdx.x*blockDim.x + threadIdx.x;
  if (i >= n4) return;
  float4 v = reinterpret_cast<const float4*>(in)[i];
  bf16* o = outp + (size_t)i*4;
  o[0] = __float2bfloat16(v.x); o[1] = __float2bfloat16(v.y);
  o[2] = __float2bfloat16(v.z); o[3] = __float2bfloat16(v.w);
}

// Wt[f*K + k] = bf16(W[k*F + f])
__global__ void k_wtrans(const float* __restrict__ W, bf16* __restrict__ Wt, int K, int F){
  int i = blockIdx.x*blockDim.x + threadIdx.x;
  if (i >= K*F) return;
  int k = i / F, f = i - k*F;
  Wt[(size_t)f*K + k] = __float2bfloat16(W[i]);
}

// ---------------- MFMA bf16 GEMM: Y[N,F](bf16) = A[N,K](bf16) @ Wt[FPAD,K]^T ----------------
// 4 waves/block, each wave owns 32 rows (2 A-fragments); B-fragments reused for both.
template<int K, int F, int FPAD>
__global__ __launch_bounds__(256) void k_gemm_mfma(const bf16* __restrict__ A, const bf16* __restrict__ Wt,
                                                   bf16* __restrict__ Y, int N){
  const int NT = FPAD/16;
  int w = threadIdx.x >> 6;       // wave 0..3
  int l = threadIdx.x & 63;       // lane
  int bm = blockIdx.x*128 + w*32;
  int r0 = bm + (l & 15);
  int r1 = r0 + 16;
  int r0c = min(r0, N-1);
  int r1c = min(r1, N-1);
  int koff = 8*(l >> 4);
  f32x4 acc0[NT], acc1[NT];
  #pragma unroll
  for (int t = 0; t < NT; t++){ acc0[t] = f32x4{0.f,0.f,0.f,0.f}; acc1[t] = f32x4{0.f,0.f,0.f,0.f}; }
  const bf16* ap0 = A + (size_t)r0c*K + koff;
  const bf16* ap1 = A + (size_t)r1c*K + koff;
  const bf16* bp  = Wt + (size_t)(l & 15)*K + koff;
  for (int k0 = 0; k0 < K; k0 += 32){
    short8 a0 = *reinterpret_cast<const short8*>(ap0 + k0);
    short8 a1 = *reinterpret_cast<const short8*>(ap1 + k0);
    #pragma unroll
    for (int t = 0; t < NT; t++){
      short8 b = *reinterpret_cast<const short8*>(bp + (size_t)t*16*K + k0);
      acc0[t] = __builtin_amdgcn_mfma_f32_16x16x32_bf16(a0, b, acc0[t], 0, 0, 0);
      acc1[t] = __builtin_amdgcn_mfma_f32_16x16x32_bf16(a1, b, acc1[t], 0, 0, 0);
    }
  }
  int orow = bm + ((l >> 4) << 2);
  int ocol = l & 15;
  #pragma unroll
  for (int t = 0; t < NT; t++){
    int c = t*16 + ocol;
    if (c >= F) break;
    #pragma unroll
    for (int jr = 0; jr < 4; jr++){
      int r = orow + jr;
      if (r < N)      Y[(size_t)r*F + c]      = __float2bfloat16(acc0[t][jr]);
      if (r + 16 < N) Y[(size_t)(r+16)*F + c] = __float2bfloat16(acc1[t][jr]);
    }
  }
}

// ---------------- attention logits per node (vectorized when C%4==0) ----------------
__global__ void k_al(const bf16* __restrict__ xl, const float* __restrict__ asrc, const float* __restrict__ adst,
                     float* __restrict__ als, float* __restrict__ ald, int N, int H, int C){
  int i = blockIdx.x*blockDim.x + threadIdx.x;
  if (i >= N*H) return;
  int h = i % H;
  const ushort* row = reinterpret_cast<const ushort*>(xl) + (size_t)(i/H)*H*C + (size_t)h*C;
  float s = 0.f, d = 0.f;
  if ((C & 3) == 0){
    for (int c = 0; c < C; c += 4){
      ushort4 v = *reinterpret_cast<const ushort4*>(row + c);
      s += u2f(v.x)*asrc[h*C+c+0] + u2f(v.y)*asrc[h*C+c+1] + u2f(v.z)*asrc[h*C+c+2] + u2f(v.w)*asrc[h*C+c+3];
      d += u2f(v.x)*adst[h*C+c+0] + u2f(v.y)*adst[h*C+c+1] + u2f(v.z)*adst[h*C+c+2] + u2f(v.w)*adst[h*C+c+3];
    }
  } else {
    for (int c = 0; c < C; c++){ float v = u2f(row[c]); s += v*asrc[h*C+c]; d += v*adst[h*C+c]; }
  }
  als[i] = s; ald[i] = d;
}

// ---------------- softmax coefs: SINGLE pass (softmax is shift-invariant; logits ≪ 88) ----------------
// w = exp(lrelu(als[src]+ald[dst])), stored unnormalized; inv = 1/sum applied in k_gat3.
template<int H>
__global__ void k_coef(const int* __restrict__ rowptr, const int* __restrict__ ssrc,
                       const float* __restrict__ als, const float* __restrict__ ald,
                       float* __restrict__ coef, float* __restrict__ invs, int N){
  int i = blockIdx.x*blockDim.x + threadIdx.x;
  if (i >= N*H) return;
  int node = i / H;
  int h = i - node*H;
  int beg = rowptr[node], end = rowptr[node+1];
  float ad = ald[i];
  float s = 0.f;
  int p = beg;
  for (; p + 8 <= end; p += 8){
    int s0=ssrc[p],   s1=ssrc[p+1], s2=ssrc[p+2], s3=ssrc[p+3];
    int s4=ssrc[p+4], s5=ssrc[p+5], s6=ssrc[p+6], s7=ssrc[p+7];
    float w0 = __expf(lrelu(als[s0*H + h] + ad));
    float w1 = __expf(lrelu(als[s1*H + h] + ad));
    float w2 = __expf(lrelu(als[s2*H + h] + ad));
    float w3 = __expf(lrelu(als[s3*H + h] + ad));
    float w4 = __expf(lrelu(als[s4*H + h] + ad));
    float w5 = __expf(lrelu(als[s5*H + h] + ad));
    float w6 = __expf(lrelu(als[s6*H + h] + ad));
    float w7 = __expf(lrelu(als[s7*H + h] + ad));
    coef[(size_t)(p+0)*H + h] = w0;
    coef[(size_t)(p+1)*H + h] = w1;
    coef[(size_t)(p+2)*H + h] = w2;
    coef[(size_t)(p+3)*H + h] = w3;
    coef[(size_t)(p+4)*H + h] = w4;
    coef[(size_t)(p+5)*H + h] = w5;
    coef[(size_t)(p+6)*H + h] = w6;
    coef[(size_t)(p+7)*H + h] = w7;
    s += (w0+w1)+(w2+w3)+((w4+w5)+(w6+w7));
  }
  for (; p < end; p++){
    float w = __expf(lrelu(als[ssrc[p]*H + h] + ad));
    coef[(size_t)p*H + h] = w;
    s += w;
  }
  invs[i] = 1.f / (s + 1e-16f);
}

// ---------------- GAT aggregation: ushort4 gather, unroll x8, bf16 output ----------------
template<int H, int C, int NPB>
__global__ void k_gat3(const int* __restrict__ rowptr, const int* __restrict__ ssrc,
                       const bf16* __restrict__ xl, const float* __restrict__ coef,
                       const float* __restrict__ invs, bf16* __restrict__ out, int N){
  const int F = H*C;
  const int TPN = F/4;
  int tid = threadIdx.x;
  int node = blockIdx.x*NPB + tid/TPN;
  int lt = (tid - (tid/TPN)*TPN)*4;    // starting feature, multiple of 4 (4 | C)
  if (node >= N) return;
  int h = lt / C;
  int beg = rowptr[node], end = rowptr[node+1];
  const float* cof = coef + h;
  const ushort* xlp = reinterpret_cast<const ushort*>(xl) + lt;
  float a0=0.f, a1=0.f, a2=0.f, a3=0.f;
  int p = beg;
  for (; p + 8 <= end; p += 8){
    int s0=ssrc[p],   s1=ssrc[p+1], s2=ssrc[p+2], s3=ssrc[p+3];
    int s4=ssrc[p+4], s5=ssrc[p+5], s6=ssrc[p+6], s7=ssrc[p+7];
    float c0 = cof[(size_t)(p+0)*H];
    float c1 = cof[(size_t)(p+1)*H];
    float c2 = cof[(size_t)(p+2)*H];
    float c3 = cof[(size_t)(p+3)*H];
    float c4 = cof[(size_t)(p+4)*H];
    float c5 = cof[(size_t)(p+5)*H];
    float c6 = cof[(size_t)(p+6)*H];
    float c7 = cof[(size_t)(p+7)*H];
    ushort4 v0 = *reinterpret_cast<const ushort4*>(xlp + (size_t)s0*F);
    ushort4 v1 = *reinterpret_cast<const ushort4*>(xlp + (size_t)s1*F);
    ushort4 v2 = *reinterpret_cast<const ushort4*>(xlp + (size_t)s2*F);
    ushort4 v3 = *reinterpret_cast<const ushort4*>(xlp + (size_t)s3*F);
    ushort4 v4 = *reinterpret_cast<const ushort4*>(xlp + (size_t)s4*F);
    ushort4 v5 = *reinterpret_cast<const ushort4*>(xlp + (size_t)s5*F);
    ushort4 v6 = *reinterpret_cast<const ushort4*>(xlp + (size_t)s6*F);
    ushort4 v7 = *reinterpret_cast<const ushort4*>(xlp + (size_t)s7*F);
    a0 += c0*u2f(v0.x); a1 += c0*u2f(v0.y); a2 += c0*u2f(v0.z); a3 += c0*u2f(v0.w);
    a0 += c1*u2f(v1.x); a1 += c1*u2f(v1.y); a2 += c1*u2f(v1.z); a3 += c1*u2f(v1.w);
    a0 += c2*u2f(v2.x); a1 += c2*u2f(v2.y); a2 += c2*u2f(v2.z); a3 += c2*u2f(v2.w);
    a0 += c3*u2f(v3.x); a1 += c3*u2f(v3.y); a2 += c3*u2f(v3.z); a3 += c3*u2f(v3.w);
    a0 += c4*u2f(v4.x); a1 += c4*u2f(v4.y); a2 += c4*u2f(v4.z); a3 += c4*u2f(v4.w);
    a0 += c5*u2f(v5.x); a1 += c5*u2f(v5.y); a2 += c5*u2f(v5.z); a3 += c5*u2f(v5.w);
    a0 += c6*u2f(v6.x); a1 += c6*u2f(v6.y); a2 += c6*u2f(v6.z); a3 += c6*u2f(v6.w);
    a0 += c7*u2f(v7.x); a1 += c7*u2f(v7.y); a2 += c7*u2f(v7.z); a3 += c7*u2f(v7.w);
  }
  for (; p < end; p++){
    int si = ssrc[p];
    float c = cof[(size_t)p*H];
    ushort4 v = *reinterpret_cast<const ushort4*>(xlp + (size_t)si*F);
    a0 += c*u2f(v.x); a1 += c*u2f(v.y); a2 += c*u2f(v.z); a3 += c*u2f(v.w);
  }
  float inv = invs[node*H + h];
  bf16 ov[4];
  ov[0] = __float2bfloat16(a0*inv);
  ov[1] = __float2bfloat16(a1*inv);
  ov[2] = __float2bfloat16(a2*inv);
  ov[3] = __float2bfloat16(a3*inv);
  *reinterpret_cast<ushort4*>(reinterpret_cast<ushort*>(out) + (size_t)node*F + lt) =
      *reinterpret_cast<ushort4*>(ov);
}

// ---------------- GAT aggregation, narrow-F path (layer 3, fp32 out) ----------------
template<int H, int C, int NPB>
__global__ void k_gat2(const int* __restrict__ rowptr, const int* __restrict__ ssrc,
                       const bf16* __restrict__ xl, const float* __restrict__ coef,
                       const float* __restrict__ invs, float* __restrict__ out, int N){
  const int F = H*C;
  int tid = threadIdx.x;
  int node = blockIdx.x*NPB + tid/F;
  int lt = tid - (tid/F)*F;
  if (node >= N) return;
  int h = lt / C;
  int beg = rowptr[node], end = rowptr[node+1];
  const float* cof = coef + h;
  const bf16* xlp = xl + lt;
  float acc = 0.f;
  int p = beg;
  for (; p + 8 <= end; p += 8){
    int s0=ssrc[p],   s1=ssrc[p+1], s2=ssrc[p+2], s3=ssrc[p+3];
    int s4=ssrc[p+4], s5=ssrc[p+5], s6=ssrc[p+6], s7=ssrc[p+7];
    float c0 = cof[(size_t)(p+0)*H];
    float c1 = cof[(size_t)(p+1)*H];
    float c2 = cof[(size_t)(p+2)*H];
    float c3 = cof[(size_t)(p+3)*H];
    float c4 = cof[(size_t)(p+4)*H];
    float c5 = cof[(size_t)(p+5)*H];
    float c6 = cof[(size_t)(p+6)*H];
    float c7 = cof[(size_t)(p+7)*H];
    float v0 = b2f(xlp[(size_t)s0*F]);
    float v1 = b2f(xlp[(size_t)s1*F]);
    float v2 = b2f(xlp[(size_t)s2*F]);
    float v3 = b2f(xlp[(size_t)s3*F]);
    float v4 = b2f(xlp[(size_t)s4*F]);
    float v5 = b2f(xlp[(size_t)s5*F]);
    float v6 = b2f(xlp[(size_t)s6*F]);
    float v7 = b2f(xlp[(size_t)s7*F]);
    acc += c0*v0; acc += c1*v1; acc += c2*v2; acc += c3*v3;
    acc += c4*v4; acc += c5*v5; acc += c6*v6; acc += c7*v7;
  }
  for (; p < end; p++){
    int si = ssrc[p];
    acc += cof[(size_t)p*H] * b2f(xlp[(size_t)si*F]);
  }
  out[(size_t)node*F + lt] = acc * invs[node*H + h];
}

// ---------------- BatchNorm (bf16 input) ----------------
__global__ void k_bnstats(const bf16* __restrict__ x, int N, int F, float* __restrict__ sums, float* __restrict__ sumsq){
  int f = threadIdx.x;
  if (f >= F) return;
  int r0 = blockIdx.x*128;
  int r1 = min(r0+128, N);
  float s=0.f, s2=0.f;
  for (int r=r0; r<r1; r++){ float v = b2f(x[(size_t)r*F + f]); s += v; s2 += v*v; }
  atomicAdd(&sums[f], s);
  atomicAdd(&sumsq[f], s2);
}

// BN + ELU: bf16 in, bf16 out (feeds the next MFMA GEMM directly)
__global__ void k_bnapply_elu(const bf16* __restrict__ x, const float* __restrict__ sums, const float* __restrict__ sumsq,
                              const float* __restrict__ g, const float* __restrict__ beta,
                              bf16* __restrict__ y, int N, int F){
  int i = blockIdx.x*blockDim.x + threadIdx.x;
  if (i >= N*F) return;
  int f = i % F;
  float mu = sums[f] / (float)N;
  float var = sumsq[f] / (float)N - mu*mu;
  float inv = rsqrtf(var + 1e-5f);
  float v = (b2f(x[i])-mu)*inv*g[f] + beta[f];
  v = v > 0.f ? v : (__expf(v) - 1.f);
  y[i] = __float2bfloat16(v);
}

// ---------------- final: +bias, log_softmax over 10 classes ----------------
__global__ void k_final(const float* __restrict__ x, const float* __restrict__ b3, float* __restrict__ out, int N){
  int n = blockIdx.x*blockDim.x + threadIdx.x;
  if (n >= N) return;
  float v[10];
  float m = -1e30f;
  #pragma unroll
  for (int c=0;c<10;c++){ v[c] = x[n*10+c] + b3[c]; m = fmaxf(m, v[c]); }
  float s = 0.f;
  #pragma unroll
  for (int c=0;c<10;c++) s += __expf(v[c]-m);
  float ls = logf(s);
  #pragma unroll
  for (int c=0;c<10;c++) out[n*10+c] = v[c] - m - ls;
}

extern "C" void kernel_launch(void* const* d_in, const int* in_sizes, int n_in,
                              void* d_out, int out_size, void* d_ws, size_t ws_size,
                              hipStream_t stream){
  const float* x   = (const float*)d_in[0];
  const int*  ei   = (const int*)d_in[1];
  const float* W1  = (const float*)d_in[2];
  const float* as1 = (const float*)d_in[3];
  const float* ad1 = (const float*)d_in[4];
  // d_in[5] = b1: cancels under BatchNorm (mean subtraction) -> skipped
  const float* g1  = (const float*)d_in[6];
  const float* be1 = (const float*)d_in[7];
  const float* W2  = (const float*)d_in[8];
  const float* as2 = (const float*)d_in[9];
  const float* ad2 = (const float*)d_in[10];
  // d_in[11] = b2: cancels under BatchNorm -> skipped
  const float* g2  = (const float*)d_in[12];
  const float* be2 = (const float*)d_in[13];
  const float* W3  = (const float*)d_in[14];
  const float* as3 = (const float*)d_in[15];
  const float* ad3 = (const float*)d_in[16];
  const float* b3  = (const float*)d_in[17];
  float* out = (float*)d_out;
  (void)n_in; (void)out_size; (void)ws_size;

  int N = in_sizes[0] / 128;     // 50000
  int E = in_sizes[1] / 2;       // 850000
  const int* src = ei;
  const int* dst = ei + E;

  char* w = (char*)d_ws;
  size_t off = 0;
  auto alloc = [&](size_t bytes) -> void* {
    void* p = w + off;
    off += (bytes + 255) & ~(size_t)255;
    return p;
  };
  bf16* xlb    = (bf16*)alloc((size_t)N*256*2);    // GEMM out (bf16), per layer
  bf16*  goutb = (bf16*)alloc((size_t)N*256*2);    // GAT out (bf16, layers 1-2)
  float* goutf = (float*)alloc((size_t)N*16*4);    // GAT out (fp32, layer 3)
  bf16*  hb    = (bf16*)alloc((size_t)N*256*2);    // BN+ELU out (bf16) = next GEMM input
  float* coef  = (float*)alloc((size_t)E*8*4);     // softmax weights (unnormalized), CSR-ordered
  bf16*  xb    = (bf16*)alloc((size_t)N*128*2);    // x cast to bf16
  bf16*  Wt1   = (bf16*)alloc((size_t)128*128*2);  // W^T bf16
  bf16*  Wt2   = (bf16*)alloc((size_t)256*128*2);
  bf16*  Wt3   = (bf16*)alloc((size_t)16*256*2);   // padded to 16 cols
  float* als   = (float*)alloc((size_t)N*8*4);
  float* ald   = (float*)alloc((size_t)N*8*4);
  float* invs  = (float*)alloc((size_t)N*8*4);
  int* rowptr  = (int*)alloc((size_t)(N+1)*4);
  int* counts  = (int*)alloc((size_t)N*4);
  int* cursor  = (int*)alloc((size_t)N*4);
  int* ssrc    = (int*)alloc((size_t)E*4);
  int* bsums   = (int*)alloc(256*4);
  float* sums  = (float*)alloc(256*4);
  float* sumsq = (float*)alloc(256*4);

  // ---- CSR by dst (reused for all 3 layers) ----
  hipMemsetAsync(counts, 0, (size_t)N*4, stream);
  hipMemsetAsync(cursor, 0, (size_t)N*4, stream);
  k_hist<<<(E+255)/256, 256, 0, stream>>>(dst, E, counts);
  int nchunks = (N + 1023)/1024;
  k_scan_block<<<nchunks, 1024, 0, stream>>>(counts, N, rowptr, bsums);
  k_scan_sums<<<1, 64, 0, stream>>>(bsums, nchunks);
  k_scan_add<<<(N+1+255)/256, 256, 0, stream>>>(rowptr, bsums, N, E);
  k_scatter<<<(E+255)/256, 256, 0, stream>>>(src, dst, E, rowptr, cursor, ssrc);

  // ---- dtype prep ----
  k_cast<<<((N*128/4)+255)/256, 256, 0, stream>>>(x, xb, N*128/4);
  k_wtrans<<<(128*128+255)/256, 256, 0, stream>>>(W1, Wt1, 128, 128);
  k_wtrans<<<(128*256+255)/256, 256, 0, stream>>>(W2, Wt2, 128, 256);
  hipMemsetAsync(Wt3, 0, (size_t)16*256*2, stream);
  k_wtrans<<<(256*10+255)/256, 256, 0, stream>>>(W3, Wt3, 256, 10);

  int gblk = (N + 127)/128;

  // ---- layer 1: x[N,128] -> h1[N,128] ----
  {
    const int F=128, H=8;
    k_gemm_mfma<128,128,128><<<gblk, 256, 0, stream>>>(xb, Wt1, xlb, N);
    k_al<<<(N*H+255)/256, 256, 0, stream>>>(xlb, as1, ad1, als, ald, N, H, 16);
    k_coef<8><<<(N*H+255)/256, 256, 0, stream>>>(rowptr, ssrc, als, ald, coef, invs, N);
    k_gat3<8,16,8><<<(N+7)/8, 256, 0, stream>>>(rowptr, ssrc, xlb, coef, invs, goutb, N);
    hipMemsetAsync(sums, 0, 256*4, stream);
    hipMemsetAsync(sumsq, 0, 256*4, stream);
    k_bnstats<<<(N+127)/128, F, 0, stream>>>(goutb, N, F, sums, sumsq);
    k_bnapply_elu<<<(int)(((size_t)N*F+255)/256), 256, 0, stream>>>(goutb, sums, sumsq, g1, be1, hb, N, F);
  }
  // ---- layer 2: h1[N,128] -> h2[N,256] ----
  {
    const int F=256, H=8;
    k_gemm_mfma<128,256,256><<<gblk, 256, 0, stream>>>(hb, Wt2, xlb, N);
    k_al<<<(N*H+255)/256, 256, 0, stream>>>(xlb, as2, ad2, als, ald, N, H, 32);
    k_coef<8><<<(N*H+255)/256, 256, 0, stream>>>(rowptr, ssrc, als, ald, coef, invs, N);
    k_gat3<8,32,4><<<(N+3)/4, 256, 0, stream>>>(rowptr, ssrc, xlb, coef, invs, goutb, N);
    hipMemsetAsync(sums, 0, 256*4, stream);
    hipMemsetAsync(sumsq, 0, 256*4, stream);
    k_bnstats<<<(N+127)/128, F, 0, stream>>>(goutb, N, F, sums, sumsq);
    k_bnapply_elu<<<(int)(((size_t)N*F+255)/256), 256, 0, stream>>>(goutb, sums, sumsq, g2, be2, hb, N, F);
  }
  // ---- layer 3: h2[N,256] -> logits[N,10] ----
  {
    const int H=1;
    k_gemm_mfma<256,10,16><<<gblk, 256, 0, stream>>>(hb, Wt3, xlb, N);
    k_al<<<(N*H+255)/256, 256, 0, stream>>>(xlb, as3, ad3, als, ald, N, H, 10);
    k_coef<1><<<(N+255)/256, 256, 0, stream>>>(rowptr, ssrc, als, ald, coef, invs, N);
    k_gat2<1,10,32><<<(N+31)/32, 320, 0, stream>>>(rowptr, ssrc, xlb, coef, invs, goutf, N);
    k_final<<<(N+255)/256, 256, 0, stream>>>(goutf, b3, out, N);
  }
}